// Round 8
// baseline (232.257 us; speedup 1.0000x reference)
//
#include <hip/hip_runtime.h>

typedef float f32x4 __attribute__((ext_vector_type(4)));
typedef float f32x16 __attribute__((ext_vector_type(16)));
typedef __bf16 bf16x8 __attribute__((ext_vector_type(8)));
typedef unsigned short u16;
typedef unsigned int u32;
typedef u16 u16x8 __attribute__((ext_vector_type(8)));
typedef u16 u16x4 __attribute__((ext_vector_type(4)));
typedef u32 u32x4 __attribute__((ext_vector_type(4)));

#define SCALE2F (0.044194173824159216f * 1.4426950408889634f)   // 1/sqrt(512) * log2(e)
#define UNSCALE (1.0f / SCALE2F)

__device__ __forceinline__ u16 f2bf(float x){ return __builtin_bit_cast(u16, (__bf16)x); }
__device__ __forceinline__ float bf2f(u16 h){ unsigned u = ((unsigned)h) << 16; return __builtin_bit_cast(float, u); }
// XOR swizzle within a 128B row: involution, bijective per 128B wrap
__device__ __forceinline__ int swz(int r, int byteInRow){ return (r*128 + byteInRow) ^ ((r & 7) << 4); }
// async global->LDS, 16B per lane; LDS dest must be wave-uniform base + lane*16
__device__ __forceinline__ void gload16(const void* g, void* l) {
  __builtin_amdgcn_global_load_lds(
      (const __attribute__((address_space(1))) void*)g,
      (__attribute__((address_space(3))) void*)l, 16, 0, 0);
}
__device__ __forceinline__ u32 cvtpk(float lo, float hi_) {
  u32 r;
  asm("v_cvt_pk_bf16_f32 %0, %1, %2" : "=v"(r) : "v"(lo), "v"(hi_));
  return r;
}
// v_permlane32_swap_b32: a' = {a.lo32, b.lo32}, b' = {a.hi32, b.hi32}
__device__ __forceinline__ void swap32(u32 &a, u32 &b) {
  asm("v_permlane32_swap_b32 %0, %1" : "+v"(a), "+v"(b));
}

#define MFMA(a,b,c)   __builtin_amdgcn_mfma_f32_16x16x32_bf16((a),(b),(c),0,0,0)
#define MFMA32(a,b,c) __builtin_amdgcn_mfma_f32_32x32x16_bf16((a),(b),(c),0,0,0)

// ---------------- weight prep: Wt[n][k] = bf16(W[k][n] * sc), 512x512 x4 ----------------
__global__ __launch_bounds__(256) void wprep_k(
    const float* __restrict__ W0, const float* __restrict__ W1,
    const float* __restrict__ W2, const float* __restrict__ W3,
    u16* __restrict__ wt)
{
  __shared__ float tile[64][68];
  const float* Ws[4] = {W0, W1, W2, W3};
  const float* W = Ws[blockIdx.z];
  const float sc = (blockIdx.z == 0) ? SCALE2F : 1.0f;   // fold softmax scale into Wq
  u16* out = wt + (size_t)blockIdx.z * 512 * 512;
  int k0 = blockIdx.x * 64, n0 = blockIdx.y * 64;
  int t = threadIdx.x;
  #pragma unroll
  for (int i = 0; i < 2; ++i) {
    int c = t + i*256; int r = c >> 3, k8 = c & 7;
    const float* src = W + (size_t)(k0 + r)*512 + n0 + k8*8;
    *(f32x4*)&tile[r][k8*8]     = *(const f32x4*)src;
    *(f32x4*)&tile[r][k8*8 + 4] = *(const f32x4*)(src + 4);
  }
  __syncthreads();
  #pragma unroll
  for (int i = 0; i < 2; ++i) {
    int c = t + i*256; int r = c >> 3, k8 = c & 7;
    u16x8 h;
    #pragma unroll
    for (int j = 0; j < 8; ++j) h[j] = f2bf(tile[k8*8 + j][r] * sc);
    *(u16x8*)(out + (size_t)(n0 + r)*512 + k0 + k8*8) = h;
  }
}

// ---------------- fused projections: z=0 Q->qbuf, z=1 K->kbuf, z=2 V->vt (transposed) ----
__global__ __launch_bounds__(512) void proj3_k(
    const float* __restrict__ Qin, const float* __restrict__ Kin,
    const u16* __restrict__ wt,
    const float* __restrict__ bq, const float* __restrict__ bk, const float* __restrict__ bv,
    u16* __restrict__ qbuf, u16* __restrict__ kbuf, u16* __restrict__ vt)
{
  __shared__ __align__(16) u16 lA[2][64*64];    // 8KB each
  __shared__ __align__(16) u16 lB[2][128*64];   // 16KB each
  int z = blockIdx.z;
  const float* A    = (z == 0) ? Qin : Kin;
  const u16*   Bt   = wt + (size_t)z * 262144;
  const float* bias = (z == 0) ? bq : (z == 1) ? bk : bv;
  const float bscale = (z == 0) ? SCALE2F : 1.0f;
  int row0 = blockIdx.x * 64, col0 = blockIdx.y * 128;
  int t = threadIdx.x, lane = t & 63, wid = t >> 6;
  int wr = wid >> 2, wc = wid & 3;              // 2x4 waves, 32x32 out each
  int l15 = lane & 15, lg = lane >> 4;
  int ar = t >> 3, ak8 = t & 7;
  int br = t >> 3;
  int bsrc = (((t & 7) << 4) ^ ((br & 7) << 4)) >> 1;
  const float* Arow = A + (size_t)row0 * 512;
  const u16*   Brow = Bt + (size_t)col0 * 512;

  f32x4 acc[2][2] = {};

  #pragma unroll
  for (int i = 0; i < 2; ++i)
    gload16(Brow + (size_t)(br + i*64)*512 + bsrc, (char*)lB[0] + i*8192 + t*16);
  {
    const float* src = Arow + (size_t)ar*512 + ak8*8;
    f32x4 x0 = *(const f32x4*)src;
    f32x4 x1 = *(const f32x4*)(src + 4);
    u16x8 h;
    #pragma unroll
    for (int j = 0; j < 4; ++j) { h[j] = f2bf(x0[j]); h[j+4] = f2bf(x1[j]); }
    *(u16x8*)((char*)lA[0] + swz(ar, ak8*16)) = h;
  }
  __syncthreads();

  int cur = 0;
  for (int k0 = 0; k0 < 512; k0 += 64) {
    bool pf = (k0 + 64 < 512);
    f32x4 px0, px1;
    if (pf) {
      #pragma unroll
      for (int i = 0; i < 2; ++i)
        gload16(Brow + (size_t)(br + i*64)*512 + k0 + 64 + bsrc, (char*)lB[cur^1] + i*8192 + t*16);
      const float* src = Arow + (size_t)ar*512 + k0 + 64 + ak8*8;
      px0 = *(const f32x4*)src;
      px1 = *(const f32x4*)(src + 4);
    }
    const char* lAc = (const char*)lA[cur];
    const char* lBc = (const char*)lB[cur];
    #pragma unroll
    for (int ks = 0; ks < 2; ++ks) {
      bf16x8 af[2], bfv[2];
      #pragma unroll
      for (int m = 0; m < 2; ++m)
        af[m] = *(const bf16x8*)(lAc + swz(wr*32 + m*16 + l15, ks*64 + lg*16));
      #pragma unroll
      for (int n = 0; n < 2; ++n)
        bfv[n] = *(const bf16x8*)(lBc + swz(wc*32 + n*16 + l15, ks*64 + lg*16));
      #pragma unroll
      for (int m = 0; m < 2; ++m)
        #pragma unroll
        for (int n = 0; n < 2; ++n)
          acc[m][n] = MFMA(af[m], bfv[n], acc[m][n]);
    }
    if (pf) {
      u16x8 h;
      #pragma unroll
      for (int j = 0; j < 4; ++j) { h[j] = f2bf(px0[j]); h[j+4] = f2bf(px1[j]); }
      *(u16x8*)((char*)lA[cur^1] + swz(ar, ak8*16)) = h;
    }
    __syncthreads();
    cur ^= 1;
  }

  if (z < 2) {
    u16* out = z ? kbuf : qbuf;
    #pragma unroll
    for (int m = 0; m < 2; ++m) {
      int rowg = row0 + wr*32 + m*16 + lg*4;
      #pragma unroll
      for (int n = 0; n < 2; ++n) {
        int colg = col0 + wc*32 + n*16 + l15;
        float bvv = bias[colg] * bscale;
        #pragma unroll
        for (int r = 0; r < 4; ++r)
          out[(size_t)(rowg + r)*512 + colg] = f2bf(acc[m][n][r] + bvv);
      }
    }
  } else {     // V: write transposed vt[b][dh][tok]
    #pragma unroll
    for (int m = 0; m < 2; ++m) {
      int rowg = row0 + wr*32 + m*16 + lg*4;
      int b = rowg >> 11, ntok = rowg & 2047;
      #pragma unroll
      for (int n = 0; n < 2; ++n) {
        int colg = col0 + wc*32 + n*16 + l15;
        float bvv = bias[colg];
        u16x4 hv;
        #pragma unroll
        for (int r = 0; r < 4; ++r) hv[r] = f2bf(acc[m][n][r] + bvv);
        *(u16x4*)(vt + ((size_t)b*512 + colg)*2048 + ntok) = hv;
      }
    }
  }
}

// ---------------- Wo GEMM: G = bf16( resid + relu(H @ Wo^T + bo) ), 64x128 tile --------
__global__ __launch_bounds__(512) void gemmo_k(
    const u16* __restrict__ A, const u16* __restrict__ Bt,
    const float* __restrict__ bias, u16* __restrict__ outb,
    const u16* __restrict__ resid)
{
  __shared__ __align__(16) u16 lA[2][64*64];
  __shared__ __align__(16) u16 lB[2][128*64];
  int row0 = blockIdx.x * 64, col0 = blockIdx.y * 128;
  int t = threadIdx.x, lane = t & 63, wid = t >> 6;
  int wr = wid >> 2, wc = wid & 3;
  int l15 = lane & 15, lg = lane >> 4;
  int ar = t >> 3;
  int asrc = (((t & 7) << 4) ^ ((ar & 7) << 4)) >> 1;
  const u16* Arow = A + (size_t)row0 * 512;
  const u16* Brow = Bt + (size_t)col0 * 512;
  f32x4 acc[2][2] = {};

  gload16(Arow + (size_t)ar*512 + asrc, (char*)lA[0] + t*16);
  #pragma unroll
  for (int i = 0; i < 2; ++i)
    gload16(Brow + (size_t)(ar + i*64)*512 + asrc, (char*)lB[0] + i*8192 + t*16);
  __syncthreads();

  int cur = 0;
  for (int k0 = 0; k0 < 512; k0 += 64) {
    if (k0 + 64 < 512) {
      gload16(Arow + (size_t)ar*512 + k0 + 64 + asrc, (char*)lA[cur^1] + t*16);
      #pragma unroll
      for (int i = 0; i < 2; ++i)
        gload16(Brow + (size_t)(ar + i*64)*512 + k0 + 64 + asrc, (char*)lB[cur^1] + i*8192 + t*16);
    }
    const char* lAc = (const char*)lA[cur];
    const char* lBc = (const char*)lB[cur];
    #pragma unroll
    for (int ks = 0; ks < 2; ++ks) {
      bf16x8 af[2], bfv[2];
      #pragma unroll
      for (int m = 0; m < 2; ++m)
        af[m] = *(const bf16x8*)(lAc + swz(wr*32 + m*16 + l15, ks*64 + lg*16));
      #pragma unroll
      for (int n = 0; n < 2; ++n)
        bfv[n] = *(const bf16x8*)(lBc + swz(wc*32 + n*16 + l15, ks*64 + lg*16));
      #pragma unroll
      for (int m = 0; m < 2; ++m)
        #pragma unroll
        for (int n = 0; n < 2; ++n)
          acc[m][n] = MFMA(af[m], bfv[n], acc[m][n]);
    }
    __syncthreads();
    cur ^= 1;
  }
  #pragma unroll
  for (int m = 0; m < 2; ++m) {
    int rowg = row0 + wr*32 + m*16 + lg*4;
    #pragma unroll
    for (int n = 0; n < 2; ++n) {
      int colg = col0 + wc*32 + n*16 + l15;
      float bvv = bias[colg];
      #pragma unroll
      for (int r = 0; r < 4; ++r) {
        size_t idx = (size_t)(rowg + r)*512 + colg;
        outb[idx] = f2bf(bf2f(resid[idx]) + fmaxf(acc[m][n][r] + bvv, 0.0f));
      }
    }
  }
}

// ---------------- flash attention: 32x32 MFMA, q=64/wave, P in registers, KV-split x4 ---
// S^T = mfma32(K, Qg): s[r] = P^T[kv = n*32 + (r&3)+8*(r>>2)+4*hi][q = l31 (+32 for B)].
// P^T B-frags built in-register: cvt_pk pairs + permlane32_swap (T12).
// O^T = mfma32(V^T, P^T), dh rows, q = l31. Unnormalized bf16 partials + per-q sums out.
__device__ __forceinline__ void mk_pb(const f32x16& s, float& ps, bf16x8& f0, bf16x8& f1) {
  float p[16];
  #pragma unroll
  for (int r = 0; r < 16; ++r) { p[r] = __builtin_amdgcn_exp2f(s[r]); ps += p[r]; }
  u32 a0 = cvtpk(p[0],  p[1]),  b0 = cvtpk(p[4],  p[5]);
  u32 a1 = cvtpk(p[2],  p[3]),  b1 = cvtpk(p[6],  p[7]);
  swap32(a0, b0); swap32(a1, b1);
  u32 a2 = cvtpk(p[8],  p[9]),  b2 = cvtpk(p[12], p[13]);
  u32 a3 = cvtpk(p[10], p[11]), b3 = cvtpk(p[14], p[15]);
  swap32(a2, b2); swap32(a3, b3);
  u32x4 w0 = {a0, a1, b0, b1};   // kv slice +0..15 : words (0,1),(2,3),(4,5),(6,7)
  u32x4 w1 = {a2, a3, b2, b3};   // kv slice +16..31
  f0 = __builtin_bit_cast(bf16x8, w0);
  f1 = __builtin_bit_cast(bf16x8, w1);
}

__global__ __launch_bounds__(256, 4) void attn_k(
    const u16* __restrict__ qb, const u16* __restrict__ kb,
    const u16* __restrict__ vt, u16* __restrict__ opart, float* __restrict__ psb)
{
  __shared__ __align__(16) u16 lK[2][64*64];   // [kv][dh], 8KB each, swizzled reads
  __shared__ __align__(16) u16 lV[2][64*64];   // [dh][kv] (V^T), swizzled reads

  int t = threadIdx.x, lane = t & 63, wid = t >> 6;
  int bh = blockIdx.y, b = bh >> 3, h = bh & 7;
  int zkv = blockIdx.z;
  int kvbeg = zkv * 512;                       // 4-way KV split, 512 KV each
  int q0 = blockIdx.x * 256 + wid * 64;        // 4 waves x 64 q-rows
  int l31 = lane & 31, hi = lane >> 5;

  const u16* kbase = kb + ((size_t)b*2048)*512 + h*64;
  const u16* vbase = vt + ((size_t)b*512 + h*64)*2048;

  // staging: 256 thr x 16B x 2 rounds per tile; linear LDS dest, inverse-swz src col
  int sr = t >> 3;                                   // 0..31
  int ssrc = ((t & 7) ^ (sr & 7)) << 3;              // element col offset

#define STAGE(buf, kvoff)                                                              \
  gload16(kbase + (size_t)((kvoff) + sr)*512 + ssrc,       (char*)lK[buf] + t*16);     \
  gload16(kbase + (size_t)((kvoff) + 32 + sr)*512 + ssrc,  (char*)lK[buf] + 4096 + t*16); \
  gload16(vbase + (size_t)sr*2048 + (kvoff) + ssrc,        (char*)lV[buf] + t*16);     \
  gload16(vbase + (size_t)(32 + sr)*2048 + (kvoff) + ssrc, (char*)lV[buf] + 4096 + t*16);

  // Q as B-operand: col q = l31, k = ks*16 + hi*8 + j; two q-groups A (q0) and B (q0+32)
  bf16x8 aqA[4], aqB[4];
  {
    const u16* qpA = qb + ((size_t)(b*2048 + q0 + l31))*512 + h*64 + hi*8;
    const u16* qpB = qpA + (size_t)32*512;
    #pragma unroll
    for (int ks = 0; ks < 4; ++ks) {
      aqA[ks] = *(const bf16x8*)(qpA + ks*16);
      aqB[ks] = *(const bf16x8*)(qpB + ks*16);
    }
  }

  f32x16 accA[2] = {}, accB[2] = {};
  float psA = 0.0f, psB = 0.0f;

  STAGE(0, kvbeg);
  __syncthreads();

  int cur = 0;
  for (int t0 = kvbeg; t0 < kvbeg + 512; t0 += 64) {
    if (t0 + 64 < kvbeg + 512) { STAGE(cur^1, t0 + 64); }
    const char* lKc = (const char*)lK[cur];
    const char* lVc = (const char*)lV[cur];
    bf16x8 pbA[4], pbB[4];
    #pragma unroll
    for (int n = 0; n < 2; ++n) {
      f32x16 s0 = {}, s1 = {};
      #pragma unroll
      for (int ks = 0; ks < 4; ++ks) {
        bf16x8 kf = *(const bf16x8*)(lKc + swz(n*32 + l31, ks*32 + hi*16));
        s0 = MFMA32(kf, aqA[ks], s0);         // K-frag read once, used twice
        s1 = MFMA32(kf, aqB[ks], s1);
      }
      mk_pb(s0, psA, pbA[2*n], pbA[2*n+1]);
      mk_pb(s1, psB, pbB[2*n], pbB[2*n+1]);
    }
    #pragma unroll
    for (int m = 0; m < 2; ++m)
      #pragma unroll
      for (int ks = 0; ks < 4; ++ks) {
        bf16x8 vf = *(const bf16x8*)(lVc + swz(m*32 + l31, ks*32 + hi*16));
        accA[m] = MFMA32(vf, pbA[ks], accA[m]);   // V-frag read once, used twice
        accB[m] = MFMA32(vf, pbB[ks], accB[m]);
      }
    __syncthreads();
    cur ^= 1;
  }
#undef STAGE
  // ---- epilogue: unnormalized bf16 O^T partials + per-q partial sums ----
  psA += __shfl_xor(psA, 32, 64);
  psB += __shfl_xor(psB, 32, 64);
  u16* oA = opart + (((size_t)zkv*4 + b)*2048 + q0 + l31)*512 + h*64;
  u16* oB = oA + (size_t)32*512;
  #pragma unroll
  for (int m = 0; m < 2; ++m)
    #pragma unroll
    for (int rq = 0; rq < 4; ++rq) {
      u16x4 hA, hB;
      #pragma unroll
      for (int e = 0; e < 4; ++e) {
        hA[e] = f2bf(accA[m][rq*4 + e]);
        hB[e] = f2bf(accB[m][rq*4 + e]);
      }
      *(u16x4*)(oA + m*32 + rq*8 + hi*4) = hA;
      *(u16x4*)(oB + m*32 + rq*8 + hi*4) = hB;
    }
  if (hi == 0) {
    psb[((size_t)zkv*32 + bh)*2048 + q0 + l31]      = psA;
    psb[((size_t)zkv*32 + bh)*2048 + q0 + 32 + l31] = psB;
  }
}

// ---------------- LN0 fused with 4-way combine + q residual (bf16 partials) ------------
__global__ __launch_bounds__(256) void ln0c_k(
    const u16* __restrict__ opart, const float* __restrict__ psb,
    const u16* __restrict__ qb, const float* __restrict__ gam,
    const float* __restrict__ bet, u16* __restrict__ yh)
{
  int t = threadIdx.x, lane = t & 63, w = t >> 6;
  size_t row = (size_t)blockIdx.x * 4 + w;           // = b*2048 + q
  int b = (int)(row >> 11), q = (int)(row & 2047);
  int head = lane >> 3;                              // 8 lanes per 64-col head
  float sa = 0.0f;
  #pragma unroll
  for (int s4 = 0; s4 < 4; ++s4)
    sa += psb[((size_t)s4*32 + b*8 + head)*2048 + q];
  float inv = 1.0f / sa;
  u16x8 qr = *(const u16x8*)(qb + row*512 + lane*8);
  float v[8];
  #pragma unroll
  for (int j = 0; j < 8; ++j) v[j] = bf2f(qr[j])*UNSCALE;
  #pragma unroll
  for (int s4 = 0; s4 < 4; ++s4) {
    u16x8 av = *(const u16x8*)(opart + ((size_t)s4*8192 + row)*512 + lane*8);
    #pragma unroll
    for (int j = 0; j < 8; ++j) v[j] += bf2f(av[j])*inv;
  }
  float s = 0.0f, ss = 0.0f;
  #pragma unroll
  for (int j = 0; j < 8; ++j) { s += v[j]; ss += v[j]*v[j]; }
  #pragma unroll
  for (int m = 1; m < 64; m <<= 1) { s += __shfl_xor(s, m, 64); ss += __shfl_xor(ss, m, 64); }
  float mu = s * (1.0f/512.0f);
  float var = ss * (1.0f/512.0f) - mu*mu;
  float rs = rsqrtf(var + 1e-5f);
  const float* gp = gam + lane*8;
  const float* bp = bet + lane*8;
  f32x4 g0 = *(const f32x4*)gp, g1 = *(const f32x4*)(gp + 4);
  f32x4 be0 = *(const f32x4*)bp, be1 = *(const f32x4*)(bp + 4);
  u16x8 hv;
  #pragma unroll
  for (int j = 0; j < 4; ++j) {
    hv[j]   = f2bf((v[j]   - mu)*rs*g0[j] + be0[j]);
    hv[j+4] = f2bf((v[j+4] - mu)*rs*g1[j] + be1[j]);
  }
  *(u16x8*)(yh + row*512 + lane*8) = hv;
}

// ---------------- final LayerNorm (bf16 in, fp32 out) ----------------
__global__ __launch_bounds__(256) void ln_k(
    const u16* __restrict__ x, const float* __restrict__ gam,
    const float* __restrict__ bet, float* __restrict__ y)
{
  int t = threadIdx.x, lane = t & 63, w = t >> 6;
  size_t row = (size_t)blockIdx.x * 4 + w;
  u16x8 xv = *(const u16x8*)(x + row*512 + lane*8);
  float v[8];
  #pragma unroll
  for (int j = 0; j < 8; ++j) v[j] = bf2f(xv[j]);
  float s = 0.0f, ss = 0.0f;
  #pragma unroll
  for (int j = 0; j < 8; ++j) { s += v[j]; ss += v[j]*v[j]; }
  #pragma unroll
  for (int m = 1; m < 64; m <<= 1) { s += __shfl_xor(s, m, 64); ss += __shfl_xor(ss, m, 64); }
  float mu = s * (1.0f/512.0f);
  float var = ss * (1.0f/512.0f) - mu*mu;
  float rs = rsqrtf(var + 1e-5f);
  const float* gp = gam + lane*8;
  const float* bp = bet + lane*8;
  f32x4 g0 = *(const f32x4*)gp, g1 = *(const f32x4*)(gp + 4);
  f32x4 b0 = *(const f32x4*)bp, b1 = *(const f32x4*)(bp + 4);
  f32x4 o0, o1;
  #pragma unroll
  for (int j = 0; j < 4; ++j) {
    o0[j] = (v[j]   - mu)*rs*g0[j] + b0[j];
    o1[j] = (v[j+4] - mu)*rs*g1[j] + b1[j];
  }
  float* yp = y + row*512 + lane*8;
  *(f32x4*)yp = o0;
  *(f32x4*)(yp + 4) = o1;
}

extern "C" void kernel_launch(void* const* d_in, const int* in_sizes, int n_in,
                              void* d_out, int out_size, void* d_ws, size_t ws_size,
                              hipStream_t stream)
{
  const float* Q   = (const float*)d_in[0];
  const float* K   = (const float*)d_in[1];
  const float* Wq  = (const float*)d_in[2];
  const float* bq  = (const float*)d_in[3];
  const float* Wk  = (const float*)d_in[4];
  const float* bk  = (const float*)d_in[5];
  const float* Wv  = (const float*)d_in[6];
  const float* bv  = (const float*)d_in[7];
  const float* Wo  = (const float*)d_in[8];
  const float* bo  = (const float*)d_in[9];
  const float* g0  = (const float*)d_in[10];
  const float* b0  = (const float*)d_in[11];
  const float* g1  = (const float*)d_in[12];
  const float* b1  = (const float*)d_in[13];

  char* ws = (char*)d_ws;
  // layout (MB): wt 0-2 | qbuf 2-10 | kbuf 10-18 (Hbuf alias after attn) | vt 18-26 |
  //              opart 26-58 (bf16, 4 splits x 8MB) | psb 58-59 | Gb 59-67.4 (bf16)
  u16*   wt    = (u16*)(ws + 0);
  u16*   qbuf  = (u16*)(ws + (2u<<20));
  u16*   kbuf  = (u16*)(ws + (10u<<20));
  u16*   vt    = (u16*)(ws + (18u<<20));
  u16*   opart = (u16*)(ws + (26u<<20));
  float* psb   = (float*)(ws + (58u<<20));
  u16*   Gb    = (u16*)(ws + (59u<<20));
  u16*   Hbuf  = (u16*)(ws + (10u<<20));    // aliases kbuf (dead after attn)

  // 1. weight transpose+convert (Wq/bq scaled by 1/sqrt(512)*log2e)
  wprep_k<<<dim3(8, 8, 4), 256, 0, stream>>>(Wq, Wk, Wv, Wo, wt);
  // 2. all three projections; V written pre-transposed
  proj3_k<<<dim3(128, 4, 3), 512, 0, stream>>>(Q, K, wt, bq, bk, bv, qbuf, kbuf, vt);
  // 3. attention, q=64/wave, P-in-register, KV-split x4 -> bf16 partials
  attn_k<<<dim3(8, 32, 4), 256, 0, stream>>>(qbuf, kbuf, vt, opart, psb);
  // 4. combine + q residual + LN0 -> Hbuf (bf16)
  ln0c_k<<<2048, 256, 0, stream>>>(opart, psb, qbuf, g0, b0, Hbuf);
  // 5. G = bf16(H + relu(H @ Wo + bo)) -> Gb
  gemmo_k<<<dim3(128, 4), 512, 0, stream>>>(Hbuf, wt + 3*262144, bo, Gb, Hbuf);
  // 6. LN1 -> out
  ln_k<<<2048, 256, 0, stream>>>(Gb, g1, b1, (float*)d_out);
}

// Round 9
// 107.314 us; speedup vs baseline: 2.1643x; 2.1643x over previous
//
#include <hip/hip_runtime.h>

typedef float f32x4 __attribute__((ext_vector_type(4)));
typedef float f32x16 __attribute__((ext_vector_type(16)));
typedef __bf16 bf16x8 __attribute__((ext_vector_type(8)));
typedef unsigned short u16;
typedef unsigned int u32;
typedef u16 u16x8 __attribute__((ext_vector_type(8)));
typedef u16 u16x4 __attribute__((ext_vector_type(4)));
typedef u32 u32x4 __attribute__((ext_vector_type(4)));

#define SCALE2F (0.044194173824159216f * 1.4426950408889634f)   // 1/sqrt(512) * log2(e)
#define UNSCALE (1.0f / SCALE2F)

__device__ __forceinline__ u16 f2bf(float x){ return __builtin_bit_cast(u16, (__bf16)x); }
__device__ __forceinline__ float bf2f(u16 h){ unsigned u = ((unsigned)h) << 16; return __builtin_bit_cast(float, u); }
// XOR swizzle within a 128B row: involution, bijective per 128B wrap
__device__ __forceinline__ int swz(int r, int byteInRow){ return (r*128 + byteInRow) ^ ((r & 7) << 4); }
// async global->LDS, 16B per lane; LDS dest must be wave-uniform base + lane*16
__device__ __forceinline__ void gload16(const void* g, void* l) {
  __builtin_amdgcn_global_load_lds(
      (const __attribute__((address_space(1))) void*)g,
      (__attribute__((address_space(3))) void*)l, 16, 0, 0);
}
__device__ __forceinline__ u32 cvtpk(float lo, float hi_) {
  u32 r;
  asm("v_cvt_pk_bf16_f32 %0, %1, %2" : "=v"(r) : "v"(lo), "v"(hi_));
  return r;
}
// v_permlane32_swap_b32: a' = {a.lo32, b.lo32}, b' = {a.hi32, b.hi32}
__device__ __forceinline__ void swap32(u32 &a, u32 &b) {
  asm("v_permlane32_swap_b32 %0, %1" : "+v"(a), "+v"(b));
}

#define MFMA(a,b,c)   __builtin_amdgcn_mfma_f32_16x16x32_bf16((a),(b),(c),0,0,0)
#define MFMA32(a,b,c) __builtin_amdgcn_mfma_f32_32x32x16_bf16((a),(b),(c),0,0,0)

// ---------------- weight prep: Wt[n][k] = bf16(W[k][n] * sc), 512x512 x4 ----------------
__global__ __launch_bounds__(256) void wprep_k(
    const float* __restrict__ W0, const float* __restrict__ W1,
    const float* __restrict__ W2, const float* __restrict__ W3,
    u16* __restrict__ wt)
{
  __shared__ float tile[64][68];
  const float* Ws[4] = {W0, W1, W2, W3};
  const float* W = Ws[blockIdx.z];
  const float sc = (blockIdx.z == 0) ? SCALE2F : 1.0f;   // fold softmax scale into Wq
  u16* out = wt + (size_t)blockIdx.z * 512 * 512;
  int k0 = blockIdx.x * 64, n0 = blockIdx.y * 64;
  int t = threadIdx.x;
  #pragma unroll
  for (int i = 0; i < 2; ++i) {
    int c = t + i*256; int r = c >> 3, k8 = c & 7;
    const float* src = W + (size_t)(k0 + r)*512 + n0 + k8*8;
    *(f32x4*)&tile[r][k8*8]     = *(const f32x4*)src;
    *(f32x4*)&tile[r][k8*8 + 4] = *(const f32x4*)(src + 4);
  }
  __syncthreads();
  #pragma unroll
  for (int i = 0; i < 2; ++i) {
    int c = t + i*256; int r = c >> 3, k8 = c & 7;
    u16x8 h;
    #pragma unroll
    for (int j = 0; j < 8; ++j) h[j] = f2bf(tile[k8*8 + j][r] * sc);
    *(u16x8*)(out + (size_t)(n0 + r)*512 + k0 + k8*8) = h;
  }
}

// ---------------- fused projections: z=0 Q->qbuf, z=1 K->kbuf, z=2 V->vt (transposed) ----
__global__ __launch_bounds__(512) void proj3_k(
    const float* __restrict__ Qin, const float* __restrict__ Kin,
    const u16* __restrict__ wt,
    const float* __restrict__ bq, const float* __restrict__ bk, const float* __restrict__ bv,
    u16* __restrict__ qbuf, u16* __restrict__ kbuf, u16* __restrict__ vt)
{
  __shared__ __align__(16) u16 lA[2][64*64];    // 8KB each
  __shared__ __align__(16) u16 lB[2][128*64];   // 16KB each
  int z = blockIdx.z;
  const float* A    = (z == 0) ? Qin : Kin;
  const u16*   Bt   = wt + (size_t)z * 262144;
  const float* bias = (z == 0) ? bq : (z == 1) ? bk : bv;
  const float bscale = (z == 0) ? SCALE2F : 1.0f;
  int row0 = blockIdx.x * 64, col0 = blockIdx.y * 128;
  int t = threadIdx.x, lane = t & 63, wid = t >> 6;
  int wr = wid >> 2, wc = wid & 3;              // 2x4 waves, 32x32 out each
  int l15 = lane & 15, lg = lane >> 4;
  int ar = t >> 3, ak8 = t & 7;
  int br = t >> 3;
  int bsrc = (((t & 7) << 4) ^ ((br & 7) << 4)) >> 1;
  const float* Arow = A + (size_t)row0 * 512;
  const u16*   Brow = Bt + (size_t)col0 * 512;

  f32x4 acc[2][2] = {};

  #pragma unroll
  for (int i = 0; i < 2; ++i)
    gload16(Brow + (size_t)(br + i*64)*512 + bsrc, (char*)lB[0] + i*8192 + t*16);
  {
    const float* src = Arow + (size_t)ar*512 + ak8*8;
    f32x4 x0 = *(const f32x4*)src;
    f32x4 x1 = *(const f32x4*)(src + 4);
    u16x8 h;
    #pragma unroll
    for (int j = 0; j < 4; ++j) { h[j] = f2bf(x0[j]); h[j+4] = f2bf(x1[j]); }
    *(u16x8*)((char*)lA[0] + swz(ar, ak8*16)) = h;
  }
  __syncthreads();

  int cur = 0;
  for (int k0 = 0; k0 < 512; k0 += 64) {
    bool pf = (k0 + 64 < 512);
    f32x4 px0, px1;
    if (pf) {
      #pragma unroll
      for (int i = 0; i < 2; ++i)
        gload16(Brow + (size_t)(br + i*64)*512 + k0 + 64 + bsrc, (char*)lB[cur^1] + i*8192 + t*16);
      const float* src = Arow + (size_t)ar*512 + k0 + 64 + ak8*8;
      px0 = *(const f32x4*)src;
      px1 = *(const f32x4*)(src + 4);
    }
    const char* lAc = (const char*)lA[cur];
    const char* lBc = (const char*)lB[cur];
    #pragma unroll
    for (int ks = 0; ks < 2; ++ks) {
      bf16x8 af[2], bfv[2];
      #pragma unroll
      for (int m = 0; m < 2; ++m)
        af[m] = *(const bf16x8*)(lAc + swz(wr*32 + m*16 + l15, ks*64 + lg*16));
      #pragma unroll
      for (int n = 0; n < 2; ++n)
        bfv[n] = *(const bf16x8*)(lBc + swz(wc*32 + n*16 + l15, ks*64 + lg*16));
      #pragma unroll
      for (int m = 0; m < 2; ++m)
        #pragma unroll
        for (int n = 0; n < 2; ++n)
          acc[m][n] = MFMA(af[m], bfv[n], acc[m][n]);
    }
    if (pf) {
      u16x8 h;
      #pragma unroll
      for (int j = 0; j < 4; ++j) { h[j] = f2bf(px0[j]); h[j+4] = f2bf(px1[j]); }
      *(u16x8*)((char*)lA[cur^1] + swz(ar, ak8*16)) = h;
    }
    __syncthreads();
    cur ^= 1;
  }

  if (z < 2) {
    u16* out = z ? kbuf : qbuf;
    #pragma unroll
    for (int m = 0; m < 2; ++m) {
      int rowg = row0 + wr*32 + m*16 + lg*4;
      #pragma unroll
      for (int n = 0; n < 2; ++n) {
        int colg = col0 + wc*32 + n*16 + l15;
        float bvv = bias[colg] * bscale;
        #pragma unroll
        for (int r = 0; r < 4; ++r)
          out[(size_t)(rowg + r)*512 + colg] = f2bf(acc[m][n][r] + bvv);
      }
    }
  } else {     // V: write transposed vt[b][dh][tok]
    #pragma unroll
    for (int m = 0; m < 2; ++m) {
      int rowg = row0 + wr*32 + m*16 + lg*4;
      int b = rowg >> 11, ntok = rowg & 2047;
      #pragma unroll
      for (int n = 0; n < 2; ++n) {
        int colg = col0 + wc*32 + n*16 + l15;
        float bvv = bias[colg];
        u16x4 hv;
        #pragma unroll
        for (int r = 0; r < 4; ++r) hv[r] = f2bf(acc[m][n][r] + bvv);
        *(u16x4*)(vt + ((size_t)b*512 + colg)*2048 + ntok) = hv;
      }
    }
  }
}

// ---------------- Wo GEMM: G = bf16( resid + relu(H @ Wo^T + bo) ), 64x128 tile --------
__global__ __launch_bounds__(512) void gemmo_k(
    const u16* __restrict__ A, const u16* __restrict__ Bt,
    const float* __restrict__ bias, u16* __restrict__ outb,
    const u16* __restrict__ resid)
{
  __shared__ __align__(16) u16 lA[2][64*64];
  __shared__ __align__(16) u16 lB[2][128*64];
  int row0 = blockIdx.x * 64, col0 = blockIdx.y * 128;
  int t = threadIdx.x, lane = t & 63, wid = t >> 6;
  int wr = wid >> 2, wc = wid & 3;
  int l15 = lane & 15, lg = lane >> 4;
  int ar = t >> 3;
  int asrc = (((t & 7) << 4) ^ ((ar & 7) << 4)) >> 1;
  const u16* Arow = A + (size_t)row0 * 512;
  const u16* Brow = Bt + (size_t)col0 * 512;
  f32x4 acc[2][2] = {};

  gload16(Arow + (size_t)ar*512 + asrc, (char*)lA[0] + t*16);
  #pragma unroll
  for (int i = 0; i < 2; ++i)
    gload16(Brow + (size_t)(ar + i*64)*512 + asrc, (char*)lB[0] + i*8192 + t*16);
  __syncthreads();

  int cur = 0;
  for (int k0 = 0; k0 < 512; k0 += 64) {
    if (k0 + 64 < 512) {
      gload16(Arow + (size_t)ar*512 + k0 + 64 + asrc, (char*)lA[cur^1] + t*16);
      #pragma unroll
      for (int i = 0; i < 2; ++i)
        gload16(Brow + (size_t)(ar + i*64)*512 + k0 + 64 + asrc, (char*)lB[cur^1] + i*8192 + t*16);
    }
    const char* lAc = (const char*)lA[cur];
    const char* lBc = (const char*)lB[cur];
    #pragma unroll
    for (int ks = 0; ks < 2; ++ks) {
      bf16x8 af[2], bfv[2];
      #pragma unroll
      for (int m = 0; m < 2; ++m)
        af[m] = *(const bf16x8*)(lAc + swz(wr*32 + m*16 + l15, ks*64 + lg*16));
      #pragma unroll
      for (int n = 0; n < 2; ++n)
        bfv[n] = *(const bf16x8*)(lBc + swz(wc*32 + n*16 + l15, ks*64 + lg*16));
      #pragma unroll
      for (int m = 0; m < 2; ++m)
        #pragma unroll
        for (int n = 0; n < 2; ++n)
          acc[m][n] = MFMA(af[m], bfv[n], acc[m][n]);
    }
    __syncthreads();
    cur ^= 1;
  }
  #pragma unroll
  for (int m = 0; m < 2; ++m) {
    int rowg = row0 + wr*32 + m*16 + lg*4;
    #pragma unroll
    for (int n = 0; n < 2; ++n) {
      int colg = col0 + wc*32 + n*16 + l15;
      float bvv = bias[colg];
      #pragma unroll
      for (int r = 0; r < 4; ++r) {
        size_t idx = (size_t)(rowg + r)*512 + colg;
        outb[idx] = f2bf(bf2f(resid[idx]) + fmaxf(acc[m][n][r] + bvv, 0.0f));
      }
    }
  }
}

// ---------------- flash attention: 32x32 MFMA, q=64/wave, P in registers, KV-split x4 ---
// S^T = mfma32(K, Qg): s[r] = P^T[kv = n*32 + (r&3)+8*(r>>2)+4*hi][q = l31 (+32 for B)].
// P^T B-frags built in-register: cvt_pk pairs + permlane32_swap (T12).
// O^T = mfma32(V^T, P^T), dh rows, q = l31. Unnormalized bf16 partials + per-q sums out.
__device__ __forceinline__ void mk_pb(const f32x16& s, float& ps, bf16x8& f0, bf16x8& f1) {
  float p[16];
  #pragma unroll
  for (int r = 0; r < 16; ++r) { p[r] = __builtin_amdgcn_exp2f(s[r]); ps += p[r]; }
  u32 a0 = cvtpk(p[0],  p[1]),  b0 = cvtpk(p[4],  p[5]);
  u32 a1 = cvtpk(p[2],  p[3]),  b1 = cvtpk(p[6],  p[7]);
  swap32(a0, b0); swap32(a1, b1);
  u32 a2 = cvtpk(p[8],  p[9]),  b2 = cvtpk(p[12], p[13]);
  u32 a3 = cvtpk(p[10], p[11]), b3 = cvtpk(p[14], p[15]);
  swap32(a2, b2); swap32(a3, b3);
  u32x4 w0 = {a0, a1, b0, b1};   // kv slice +0..15 : words (0,1),(2,3),(4,5),(6,7)
  u32x4 w1 = {a2, a3, b2, b3};   // kv slice +16..31
  f0 = __builtin_bit_cast(bf16x8, w0);
  f1 = __builtin_bit_cast(bf16x8, w1);
}

// NOTE: (256,2) NOT (256,4) — the tighter bound forced VGPR 120->64 and spilled
// the accumulators to scratch (r8: WRITE_SIZE 17->297MB, 3.5x slower). At 120 VGPR
// the HW still runs 4 waves/SIMD (occupancy steps at 128).
__global__ __launch_bounds__(256, 2) void attn_k(
    const u16* __restrict__ qb, const u16* __restrict__ kb,
    const u16* __restrict__ vt, u16* __restrict__ opart, float* __restrict__ psb)
{
  __shared__ __align__(16) u16 lK[2][64*64];   // [kv][dh], 8KB each, swizzled reads
  __shared__ __align__(16) u16 lV[2][64*64];   // [dh][kv] (V^T), swizzled reads

  int t = threadIdx.x, lane = t & 63, wid = t >> 6;
  int bh = blockIdx.y, b = bh >> 3, h = bh & 7;
  int zkv = blockIdx.z;
  int kvbeg = zkv * 512;                       // 4-way KV split, 512 KV each
  int q0 = blockIdx.x * 256 + wid * 64;        // 4 waves x 64 q-rows
  int l31 = lane & 31, hi = lane >> 5;

  const u16* kbase = kb + ((size_t)b*2048)*512 + h*64;
  const u16* vbase = vt + ((size_t)b*512 + h*64)*2048;

  // staging: 256 thr x 16B x 2 rounds per tile; linear LDS dest, inverse-swz src col
  int sr = t >> 3;                                   // 0..31
  int ssrc = ((t & 7) ^ (sr & 7)) << 3;              // element col offset

#define STAGE(buf, kvoff)                                                              \
  gload16(kbase + (size_t)((kvoff) + sr)*512 + ssrc,       (char*)lK[buf] + t*16);     \
  gload16(kbase + (size_t)((kvoff) + 32 + sr)*512 + ssrc,  (char*)lK[buf] + 4096 + t*16); \
  gload16(vbase + (size_t)sr*2048 + (kvoff) + ssrc,        (char*)lV[buf] + t*16);     \
  gload16(vbase + (size_t)(32 + sr)*2048 + (kvoff) + ssrc, (char*)lV[buf] + 4096 + t*16);

  // Q as B-operand: col q = l31, k = ks*16 + hi*8 + j; two q-groups A (q0) and B (q0+32)
  bf16x8 aqA[4], aqB[4];
  {
    const u16* qpA = qb + ((size_t)(b*2048 + q0 + l31))*512 + h*64 + hi*8;
    const u16* qpB = qpA + (size_t)32*512;
    #pragma unroll
    for (int ks = 0; ks < 4; ++ks) {
      aqA[ks] = *(const bf16x8*)(qpA + ks*16);
      aqB[ks] = *(const bf16x8*)(qpB + ks*16);
    }
  }

  f32x16 accA[2] = {}, accB[2] = {};
  float psA = 0.0f, psB = 0.0f;

  STAGE(0, kvbeg);
  __syncthreads();

  int cur = 0;
  for (int t0 = kvbeg; t0 < kvbeg + 512; t0 += 64) {
    if (t0 + 64 < kvbeg + 512) { STAGE(cur^1, t0 + 64); }
    const char* lKc = (const char*)lK[cur];
    const char* lVc = (const char*)lV[cur];
    bf16x8 pbA[4], pbB[4];
    #pragma unroll
    for (int n = 0; n < 2; ++n) {
      f32x16 s0 = {}, s1 = {};
      #pragma unroll
      for (int ks = 0; ks < 4; ++ks) {
        bf16x8 kf = *(const bf16x8*)(lKc + swz(n*32 + l31, ks*32 + hi*16));
        s0 = MFMA32(kf, aqA[ks], s0);         // K-frag read once, used twice
        s1 = MFMA32(kf, aqB[ks], s1);
      }
      mk_pb(s0, psA, pbA[2*n], pbA[2*n+1]);
      mk_pb(s1, psB, pbB[2*n], pbB[2*n+1]);
    }
    #pragma unroll
    for (int m = 0; m < 2; ++m)
      #pragma unroll
      for (int ks = 0; ks < 4; ++ks) {
        bf16x8 vf = *(const bf16x8*)(lVc + swz(m*32 + l31, ks*32 + hi*16));
        accA[m] = MFMA32(vf, pbA[ks], accA[m]);   // V-frag read once, used twice
        accB[m] = MFMA32(vf, pbB[ks], accB[m]);
      }
    __syncthreads();
    cur ^= 1;
  }
#undef STAGE
  // ---- epilogue: unnormalized bf16 O^T partials + per-q partial sums ----
  psA += __shfl_xor(psA, 32, 64);
  psB += __shfl_xor(psB, 32, 64);
  u16* oA = opart + (((size_t)zkv*4 + b)*2048 + q0 + l31)*512 + h*64;
  u16* oB = oA + (size_t)32*512;
  #pragma unroll
  for (int m = 0; m < 2; ++m)
    #pragma unroll
    for (int rq = 0; rq < 4; ++rq) {
      u16x4 hA, hB;
      #pragma unroll
      for (int e = 0; e < 4; ++e) {
        hA[e] = f2bf(accA[m][rq*4 + e]);
        hB[e] = f2bf(accB[m][rq*4 + e]);
      }
      *(u16x4*)(oA + m*32 + rq*8 + hi*4) = hA;
      *(u16x4*)(oB + m*32 + rq*8 + hi*4) = hB;
    }
  if (hi == 0) {
    psb[((size_t)zkv*32 + bh)*2048 + q0 + l31]      = psA;
    psb[((size_t)zkv*32 + bh)*2048 + q0 + 32 + l31] = psB;
  }
}

// ---------------- LN0 fused with 4-way combine + q residual (bf16 partials) ------------
__global__ __launch_bounds__(256) void ln0c_k(
    const u16* __restrict__ opart, const float* __restrict__ psb,
    const u16* __restrict__ qb, const float* __restrict__ gam,
    const float* __restrict__ bet, u16* __restrict__ yh)
{
  int t = threadIdx.x, lane = t & 63, w = t >> 6;
  size_t row = (size_t)blockIdx.x * 4 + w;           // = b*2048 + q
  int b = (int)(row >> 11), q = (int)(row & 2047);
  int head = lane >> 3;                              // 8 lanes per 64-col head
  float sa = 0.0f;
  #pragma unroll
  for (int s4 = 0; s4 < 4; ++s4)
    sa += psb[((size_t)s4*32 + b*8 + head)*2048 + q];
  float inv = 1.0f / sa;
  u16x8 qr = *(const u16x8*)(qb + row*512 + lane*8);
  float v[8];
  #pragma unroll
  for (int j = 0; j < 8; ++j) v[j] = bf2f(qr[j])*UNSCALE;
  #pragma unroll
  for (int s4 = 0; s4 < 4; ++s4) {
    u16x8 av = *(const u16x8*)(opart + ((size_t)s4*8192 + row)*512 + lane*8);
    #pragma unroll
    for (int j = 0; j < 8; ++j) v[j] += bf2f(av[j])*inv;
  }
  float s = 0.0f, ss = 0.0f;
  #pragma unroll
  for (int j = 0; j < 8; ++j) { s += v[j]; ss += v[j]*v[j]; }
  #pragma unroll
  for (int m = 1; m < 64; m <<= 1) { s += __shfl_xor(s, m, 64); ss += __shfl_xor(ss, m, 64); }
  float mu = s * (1.0f/512.0f);
  float var = ss * (1.0f/512.0f) - mu*mu;
  float rs = rsqrtf(var + 1e-5f);
  const float* gp = gam + lane*8;
  const float* bp = bet + lane*8;
  f32x4 g0 = *(const f32x4*)gp, g1 = *(const f32x4*)(gp + 4);
  f32x4 be0 = *(const f32x4*)bp, be1 = *(const f32x4*)(bp + 4);
  u16x8 hv;
  #pragma unroll
  for (int j = 0; j < 4; ++j) {
    hv[j]   = f2bf((v[j]   - mu)*rs*g0[j] + be0[j]);
    hv[j+4] = f2bf((v[j+4] - mu)*rs*g1[j] + be1[j]);
  }
  *(u16x8*)(yh + row*512 + lane*8) = hv;
}

// ---------------- final LayerNorm (bf16 in, fp32 out) ----------------
__global__ __launch_bounds__(256) void ln_k(
    const u16* __restrict__ x, const float* __restrict__ gam,
    const float* __restrict__ bet, float* __restrict__ y)
{
  int t = threadIdx.x, lane = t & 63, w = t >> 6;
  size_t row = (size_t)blockIdx.x * 4 + w;
  u16x8 xv = *(const u16x8*)(x + row*512 + lane*8);
  float v[8];
  #pragma unroll
  for (int j = 0; j < 8; ++j) v[j] = bf2f(xv[j]);
  float s = 0.0f, ss = 0.0f;
  #pragma unroll
  for (int j = 0; j < 8; ++j) { s += v[j]; ss += v[j]*v[j]; }
  #pragma unroll
  for (int m = 1; m < 64; m <<= 1) { s += __shfl_xor(s, m, 64); ss += __shfl_xor(ss, m, 64); }
  float mu = s * (1.0f/512.0f);
  float var = ss * (1.0f/512.0f) - mu*mu;
  float rs = rsqrtf(var + 1e-5f);
  const float* gp = gam + lane*8;
  const float* bp = bet + lane*8;
  f32x4 g0 = *(const f32x4*)gp, g1 = *(const f32x4*)(gp + 4);
  f32x4 b0 = *(const f32x4*)bp, b1 = *(const f32x4*)(bp + 4);
  f32x4 o0, o1;
  #pragma unroll
  for (int j = 0; j < 4; ++j) {
    o0[j] = (v[j]   - mu)*rs*g0[j] + b0[j];
    o1[j] = (v[j+4] - mu)*rs*g1[j] + b1[j];
  }
  float* yp = y + row*512 + lane*8;
  *(f32x4*)yp = o0;
  *(f32x4*)(yp + 4) = o1;
}

extern "C" void kernel_launch(void* const* d_in, const int* in_sizes, int n_in,
                              void* d_out, int out_size, void* d_ws, size_t ws_size,
                              hipStream_t stream)
{
  const float* Q   = (const float*)d_in[0];
  const float* K   = (const float*)d_in[1];
  const float* Wq  = (const float*)d_in[2];
  const float* bq  = (const float*)d_in[3];
  const float* Wk  = (const float*)d_in[4];
  const float* bk  = (const float*)d_in[5];
  const float* Wv  = (const float*)d_in[6];
  const float* bv  = (const float*)d_in[7];
  const float* Wo  = (const float*)d_in[8];
  const float* bo  = (const float*)d_in[9];
  const float* g0  = (const float*)d_in[10];
  const float* b0  = (const float*)d_in[11];
  const float* g1  = (const float*)d_in[12];
  const float* b1  = (const float*)d_in[13];

  char* ws = (char*)d_ws;
  // layout (MB): wt 0-2 | qbuf 2-10 | kbuf 10-18 (Hbuf alias after attn) | vt 18-26 |
  //              opart 26-58 (bf16, 4 splits x 8MB) | psb 58-59 | Gb 59-67.4 (bf16)
  u16*   wt    = (u16*)(ws + 0);
  u16*   qbuf  = (u16*)(ws + (2u<<20));
  u16*   kbuf  = (u16*)(ws + (10u<<20));
  u16*   vt    = (u16*)(ws + (18u<<20));
  u16*   opart = (u16*)(ws + (26u<<20));
  float* psb   = (float*)(ws + (58u<<20));
  u16*   Gb    = (u16*)(ws + (59u<<20));
  u16*   Hbuf  = (u16*)(ws + (10u<<20));    // aliases kbuf (dead after attn)

  // 1. weight transpose+convert (Wq/bq scaled by 1/sqrt(512)*log2e)
  wprep_k<<<dim3(8, 8, 4), 256, 0, stream>>>(Wq, Wk, Wv, Wo, wt);
  // 2. all three projections; V written pre-transposed
  proj3_k<<<dim3(128, 4, 3), 512, 0, stream>>>(Q, K, wt, bq, bk, bv, qbuf, kbuf, vt);
  // 3. attention, q=64/wave, P-in-register, KV-split x4 -> bf16 partials
  attn_k<<<dim3(8, 32, 4), 256, 0, stream>>>(qbuf, kbuf, vt, opart, psb);
  // 4. combine + q residual + LN0 -> Hbuf (bf16)
  ln0c_k<<<2048, 256, 0, stream>>>(opart, psb, qbuf, g0, b0, Hbuf);
  // 5. G = bf16(H + relu(H @ Wo + bo)) -> Gb
  gemmo_k<<<dim3(128, 4), 512, 0, stream>>>(Hbuf, wt + 3*262144, bo, Gb, Hbuf);
  // 6. LN1 -> out
  ln_k<<<2048, 256, 0, stream>>>(Gb, g1, b1, (float*)d_out);
}

// Round 10
// 101.011 us; speedup vs baseline: 2.2993x; 1.0624x over previous
//
#include <hip/hip_runtime.h>

typedef float f32x4 __attribute__((ext_vector_type(4)));
typedef float f32x16 __attribute__((ext_vector_type(16)));
typedef __bf16 bf16x8 __attribute__((ext_vector_type(8)));
typedef unsigned short u16;
typedef unsigned int u32;
typedef u16 u16x8 __attribute__((ext_vector_type(8)));
typedef u16 u16x4 __attribute__((ext_vector_type(4)));
typedef u32 u32x4 __attribute__((ext_vector_type(4)));

#define SCALE2F (0.044194173824159216f * 1.4426950408889634f)   // 1/sqrt(512) * log2(e)
#define UNSCALE (1.0f / SCALE2F)

__device__ __forceinline__ u16 f2bf(float x){ return __builtin_bit_cast(u16, (__bf16)x); }
__device__ __forceinline__ float bf2f(u16 h){ unsigned u = ((unsigned)h) << 16; return __builtin_bit_cast(float, u); }
// XOR swizzle within a 128B row: involution, bijective per 128B wrap
__device__ __forceinline__ int swz(int r, int byteInRow){ return (r*128 + byteInRow) ^ ((r & 7) << 4); }
// async global->LDS, 16B per lane; LDS dest must be wave-uniform base + lane*16
__device__ __forceinline__ void gload16(const void* g, void* l) {
  __builtin_amdgcn_global_load_lds(
      (const __attribute__((address_space(1))) void*)g,
      (__attribute__((address_space(3))) void*)l, 16, 0, 0);
}
__device__ __forceinline__ u32 cvtpk(float lo, float hi_) {
  u32 r;
  asm("v_cvt_pk_bf16_f32 %0, %1, %2" : "=v"(r) : "v"(lo), "v"(hi_));
  return r;
}
// v_permlane32_swap_b32: a' = {a.lo32, b.lo32}, b' = {a.hi32, b.hi32}
__device__ __forceinline__ void swap32(u32 &a, u32 &b) {
  asm("v_permlane32_swap_b32 %0, %1" : "+v"(a), "+v"(b));
}

#define MFMA(a,b,c)   __builtin_amdgcn_mfma_f32_16x16x32_bf16((a),(b),(c),0,0,0)
#define MFMA32(a,b,c) __builtin_amdgcn_mfma_f32_32x32x16_bf16((a),(b),(c),0,0,0)

// ---------------- weight prep: Wt[n][k] = bf16(W[k][n] * sc), 512x512 x4 ----------------
__global__ __launch_bounds__(256) void wprep_k(
    const float* __restrict__ W0, const float* __restrict__ W1,
    const float* __restrict__ W2, const float* __restrict__ W3,
    u16* __restrict__ wt)
{
  __shared__ float tile[64][68];
  const float* Ws[4] = {W0, W1, W2, W3};
  const float* W = Ws[blockIdx.z];
  const float sc = (blockIdx.z == 0) ? SCALE2F : 1.0f;   // fold softmax scale into Wq
  u16* out = wt + (size_t)blockIdx.z * 512 * 512;
  int k0 = blockIdx.x * 64, n0 = blockIdx.y * 64;
  int t = threadIdx.x;
  #pragma unroll
  for (int i = 0; i < 2; ++i) {
    int c = t + i*256; int r = c >> 3, k8 = c & 7;
    const float* src = W + (size_t)(k0 + r)*512 + n0 + k8*8;
    *(f32x4*)&tile[r][k8*8]     = *(const f32x4*)src;
    *(f32x4*)&tile[r][k8*8 + 4] = *(const f32x4*)(src + 4);
  }
  __syncthreads();
  #pragma unroll
  for (int i = 0; i < 2; ++i) {
    int c = t + i*256; int r = c >> 3, k8 = c & 7;
    u16x8 h;
    #pragma unroll
    for (int j = 0; j < 8; ++j) h[j] = f2bf(tile[k8*8 + j][r] * sc);
    *(u16x8*)(out + (size_t)(n0 + r)*512 + k0 + k8*8) = h;
  }
}

// ---------------- fused projections: z=0 Q->qbuf, z=1 K->kbuf, z=2 V->vt (transposed) ----
__global__ __launch_bounds__(512) void proj3_k(
    const float* __restrict__ Qin, const float* __restrict__ Kin,
    const u16* __restrict__ wt,
    const float* __restrict__ bq, const float* __restrict__ bk, const float* __restrict__ bv,
    u16* __restrict__ qbuf, u16* __restrict__ kbuf, u16* __restrict__ vt)
{
  __shared__ __align__(16) u16 lA[2][64*64];    // 8KB each
  __shared__ __align__(16) u16 lB[2][128*64];   // 16KB each
  int z = blockIdx.z;
  const float* A    = (z == 0) ? Qin : Kin;
  const u16*   Bt   = wt + (size_t)z * 262144;
  const float* bias = (z == 0) ? bq : (z == 1) ? bk : bv;
  const float bscale = (z == 0) ? SCALE2F : 1.0f;
  int row0 = blockIdx.x * 64, col0 = blockIdx.y * 128;
  int t = threadIdx.x, lane = t & 63, wid = t >> 6;
  int wr = wid >> 2, wc = wid & 3;              // 2x4 waves, 32x32 out each
  int l15 = lane & 15, lg = lane >> 4;
  int ar = t >> 3, ak8 = t & 7;
  int br = t >> 3;
  int bsrc = (((t & 7) << 4) ^ ((br & 7) << 4)) >> 1;
  const float* Arow = A + (size_t)row0 * 512;
  const u16*   Brow = Bt + (size_t)col0 * 512;

  f32x4 acc[2][2] = {};

  #pragma unroll
  for (int i = 0; i < 2; ++i)
    gload16(Brow + (size_t)(br + i*64)*512 + bsrc, (char*)lB[0] + i*8192 + t*16);
  {
    const float* src = Arow + (size_t)ar*512 + ak8*8;
    f32x4 x0 = *(const f32x4*)src;
    f32x4 x1 = *(const f32x4*)(src + 4);
    u16x8 h;
    #pragma unroll
    for (int j = 0; j < 4; ++j) { h[j] = f2bf(x0[j]); h[j+4] = f2bf(x1[j]); }
    *(u16x8*)((char*)lA[0] + swz(ar, ak8*16)) = h;
  }
  __syncthreads();

  int cur = 0;
  for (int k0 = 0; k0 < 512; k0 += 64) {
    bool pf = (k0 + 64 < 512);
    f32x4 px0, px1;
    if (pf) {
      #pragma unroll
      for (int i = 0; i < 2; ++i)
        gload16(Brow + (size_t)(br + i*64)*512 + k0 + 64 + bsrc, (char*)lB[cur^1] + i*8192 + t*16);
      const float* src = Arow + (size_t)ar*512 + k0 + 64 + ak8*8;
      px0 = *(const f32x4*)src;
      px1 = *(const f32x4*)(src + 4);
    }
    const char* lAc = (const char*)lA[cur];
    const char* lBc = (const char*)lB[cur];
    #pragma unroll
    for (int ks = 0; ks < 2; ++ks) {
      bf16x8 af[2], bfv[2];
      #pragma unroll
      for (int m = 0; m < 2; ++m)
        af[m] = *(const bf16x8*)(lAc + swz(wr*32 + m*16 + l15, ks*64 + lg*16));
      #pragma unroll
      for (int n = 0; n < 2; ++n)
        bfv[n] = *(const bf16x8*)(lBc + swz(wc*32 + n*16 + l15, ks*64 + lg*16));
      #pragma unroll
      for (int m = 0; m < 2; ++m)
        #pragma unroll
        for (int n = 0; n < 2; ++n)
          acc[m][n] = MFMA(af[m], bfv[n], acc[m][n]);
    }
    if (pf) {
      u16x8 h;
      #pragma unroll
      for (int j = 0; j < 4; ++j) { h[j] = f2bf(px0[j]); h[j+4] = f2bf(px1[j]); }
      *(u16x8*)((char*)lA[cur^1] + swz(ar, ak8*16)) = h;
    }
    __syncthreads();
    cur ^= 1;
  }

  if (z < 2) {
    u16* out = z ? kbuf : qbuf;
    #pragma unroll
    for (int m = 0; m < 2; ++m) {
      int rowg = row0 + wr*32 + m*16 + lg*4;
      #pragma unroll
      for (int n = 0; n < 2; ++n) {
        int colg = col0 + wc*32 + n*16 + l15;
        float bvv = bias[colg] * bscale;
        #pragma unroll
        for (int r = 0; r < 4; ++r)
          out[(size_t)(rowg + r)*512 + colg] = f2bf(acc[m][n][r] + bvv);
      }
    }
  } else {     // V: write transposed vt[b][dh][tok]
    #pragma unroll
    for (int m = 0; m < 2; ++m) {
      int rowg = row0 + wr*32 + m*16 + lg*4;
      int b = rowg >> 11, ntok = rowg & 2047;
      #pragma unroll
      for (int n = 0; n < 2; ++n) {
        int colg = col0 + wc*32 + n*16 + l15;
        float bvv = bias[colg];
        u16x4 hv;
        #pragma unroll
        for (int r = 0; r < 4; ++r) hv[r] = f2bf(acc[m][n][r] + bvv);
        *(u16x4*)(vt + ((size_t)b*512 + colg)*2048 + ntok) = hv;
      }
    }
  }
}

// ---------------- Wo GEMM: G = bf16( resid + relu(H @ Wo^T + bo) ), 64x128 tile --------
__global__ __launch_bounds__(512) void gemmo_k(
    const u16* __restrict__ A, const u16* __restrict__ Bt,
    const float* __restrict__ bias, u16* __restrict__ outb,
    const u16* __restrict__ resid)
{
  __shared__ __align__(16) u16 lA[2][64*64];
  __shared__ __align__(16) u16 lB[2][128*64];
  int row0 = blockIdx.x * 64, col0 = blockIdx.y * 128;
  int t = threadIdx.x, lane = t & 63, wid = t >> 6;
  int wr = wid >> 2, wc = wid & 3;
  int l15 = lane & 15, lg = lane >> 4;
  int ar = t >> 3;
  int asrc = (((t & 7) << 4) ^ ((ar & 7) << 4)) >> 1;
  const u16* Arow = A + (size_t)row0 * 512;
  const u16* Brow = Bt + (size_t)col0 * 512;
  f32x4 acc[2][2] = {};

  gload16(Arow + (size_t)ar*512 + asrc, (char*)lA[0] + t*16);
  #pragma unroll
  for (int i = 0; i < 2; ++i)
    gload16(Brow + (size_t)(ar + i*64)*512 + asrc, (char*)lB[0] + i*8192 + t*16);
  __syncthreads();

  int cur = 0;
  for (int k0 = 0; k0 < 512; k0 += 64) {
    if (k0 + 64 < 512) {
      gload16(Arow + (size_t)ar*512 + k0 + 64 + asrc, (char*)lA[cur^1] + t*16);
      #pragma unroll
      for (int i = 0; i < 2; ++i)
        gload16(Brow + (size_t)(ar + i*64)*512 + k0 + 64 + asrc, (char*)lB[cur^1] + i*8192 + t*16);
    }
    const char* lAc = (const char*)lA[cur];
    const char* lBc = (const char*)lB[cur];
    #pragma unroll
    for (int ks = 0; ks < 2; ++ks) {
      bf16x8 af[2], bfv[2];
      #pragma unroll
      for (int m = 0; m < 2; ++m)
        af[m] = *(const bf16x8*)(lAc + swz(wr*32 + m*16 + l15, ks*64 + lg*16));
      #pragma unroll
      for (int n = 0; n < 2; ++n)
        bfv[n] = *(const bf16x8*)(lBc + swz(wc*32 + n*16 + l15, ks*64 + lg*16));
      #pragma unroll
      for (int m = 0; m < 2; ++m)
        #pragma unroll
        for (int n = 0; n < 2; ++n)
          acc[m][n] = MFMA(af[m], bfv[n], acc[m][n]);
    }
    __syncthreads();
    cur ^= 1;
  }
  #pragma unroll
  for (int m = 0; m < 2; ++m) {
    int rowg = row0 + wr*32 + m*16 + lg*4;
    #pragma unroll
    for (int n = 0; n < 2; ++n) {
      int colg = col0 + wc*32 + n*16 + l15;
      float bvv = bias[colg];
      #pragma unroll
      for (int r = 0; r < 4; ++r) {
        size_t idx = (size_t)(rowg + r)*512 + colg;
        outb[idx] = f2bf(bf2f(resid[idx]) + fmaxf(acc[m][n][r] + bvv, 0.0f));
      }
    }
  }
}

// ---------------- flash attention: 32x32 MFMA, q=64/wave, P in registers, KV-split x2 ---
// T4: 3-buffer LDS ring, 2-deep prefetch, counted s_waitcnt vmcnt(4) + raw s_barrier
// (the per-tile __syncthreads vmcnt(0) drain was the exposed-latency stall at 2 waves/SIMD;
//  register bracket 120 VGPR + 64 AGPR = ~184 unified caps occupancy at 2 waves/SIMD, so
//  the stall cannot be hidden by TLP — it must be removed structurally).
__device__ __forceinline__ void mk_pb(const f32x16& s, float& ps, bf16x8& f0, bf16x8& f1) {
  float p[16];
  #pragma unroll
  for (int r = 0; r < 16; ++r) { p[r] = __builtin_amdgcn_exp2f(s[r]); ps += p[r]; }
  u32 a0 = cvtpk(p[0],  p[1]),  b0 = cvtpk(p[4],  p[5]);
  u32 a1 = cvtpk(p[2],  p[3]),  b1 = cvtpk(p[6],  p[7]);
  swap32(a0, b0); swap32(a1, b1);
  u32 a2 = cvtpk(p[8],  p[9]),  b2 = cvtpk(p[12], p[13]);
  u32 a3 = cvtpk(p[10], p[11]), b3 = cvtpk(p[14], p[15]);
  swap32(a2, b2); swap32(a3, b3);
  u32x4 w0 = {a0, a1, b0, b1};   // kv slice +0..15 : words (0,1),(2,3),(4,5),(6,7)
  u32x4 w1 = {a2, a3, b2, b3};   // kv slice +16..31
  f0 = __builtin_bit_cast(bf16x8, w0);
  f1 = __builtin_bit_cast(bf16x8, w1);
}

__global__ __launch_bounds__(256, 2) void attn_k(
    const u16* __restrict__ qb, const u16* __restrict__ kb,
    const u16* __restrict__ vt, u16* __restrict__ opart, float* __restrict__ psb)
{
  __shared__ __align__(16) u16 lK[3][64*64];   // [kv][dh] ring, 8KB each, swizzled reads
  __shared__ __align__(16) u16 lV[3][64*64];   // [dh][kv] (V^T) ring, swizzled reads

  int t = threadIdx.x, lane = t & 63, wid = t >> 6;
  int bh = blockIdx.y, b = bh >> 3, h = bh & 7;
  int zkv = blockIdx.z;
  int kvbeg = zkv * 1024;                      // 2-way KV split, 1024 KV each, 16 tiles
  int q0 = blockIdx.x * 256 + wid * 64;        // 4 waves x 64 q-rows
  int l31 = lane & 31, hi = lane >> 5;
  const int NT = 16;

  const u16* kbase = kb + ((size_t)b*2048)*512 + h*64;
  const u16* vbase = vt + ((size_t)b*512 + h*64)*2048;

  // staging: per call each thread issues 4 gload16 (K tile 8KB + V tile 8KB total)
  int sr = t >> 3;                                   // 0..31
  int ssrc = ((t & 7) ^ (sr & 7)) << 3;              // inverse-swizzled src col (elements)

#define STAGE(buf, kvoff)                                                              \
  gload16(kbase + (size_t)((kvoff) + sr)*512 + ssrc,       (char*)lK[buf] + t*16);     \
  gload16(kbase + (size_t)((kvoff) + 32 + sr)*512 + ssrc,  (char*)lK[buf] + 4096 + t*16); \
  gload16(vbase + (size_t)sr*2048 + (kvoff) + ssrc,        (char*)lV[buf] + t*16);     \
  gload16(vbase + (size_t)(32 + sr)*2048 + (kvoff) + ssrc, (char*)lV[buf] + 4096 + t*16);

  // Q as B-operand: col q = l31, k = ks*16 + hi*8 + j; two q-groups A (q0) and B (q0+32)
  bf16x8 aqA[4], aqB[4];
  {
    const u16* qpA = qb + ((size_t)(b*2048 + q0 + l31))*512 + h*64 + hi*8;
    const u16* qpB = qpA + (size_t)32*512;
    #pragma unroll
    for (int ks = 0; ks < 4; ++ks) {
      aqA[ks] = *(const bf16x8*)(qpA + ks*16);
      aqB[ks] = *(const bf16x8*)(qpB + ks*16);
    }
  }

  f32x16 accA[2] = {}, accB[2] = {};
  float psA = 0.0f, psB = 0.0f;

  // prologue: stage tiles 0 and 1; wait only for tile 0 (counted)
  STAGE(0, kvbeg);
  STAGE(1, kvbeg + 64);
  asm volatile("s_waitcnt vmcnt(4)" ::: "memory");
  __builtin_amdgcn_s_barrier();
  __builtin_amdgcn_sched_barrier(0);

  int rd = 0, wr2 = 2;
  for (int i = 0; i < NT; ++i) {
    int t0 = kvbeg + i*64;
    if (i + 2 < NT) { STAGE(wr2, t0 + 128); }       // 2-deep prefetch into ring
    const char* lKc = (const char*)lK[rd];
    const char* lVc = (const char*)lV[rd];
    bf16x8 pbA[4], pbB[4];
    #pragma unroll
    for (int n = 0; n < 2; ++n) {
      f32x16 s0 = {}, s1 = {};
      __builtin_amdgcn_s_setprio(1);
      #pragma unroll
      for (int ks = 0; ks < 4; ++ks) {
        bf16x8 kf = *(const bf16x8*)(lKc + swz(n*32 + l31, ks*32 + hi*16));
        s0 = MFMA32(kf, aqA[ks], s0);         // K-frag read once, used twice
        s1 = MFMA32(kf, aqB[ks], s1);
      }
      __builtin_amdgcn_s_setprio(0);
      mk_pb(s0, psA, pbA[2*n], pbA[2*n+1]);
      mk_pb(s1, psB, pbB[2*n], pbB[2*n+1]);
    }
    __builtin_amdgcn_s_setprio(1);
    #pragma unroll
    for (int m = 0; m < 2; ++m)
      #pragma unroll
      for (int ks = 0; ks < 4; ++ks) {
        bf16x8 vf = *(const bf16x8*)(lVc + swz(m*32 + l31, ks*32 + hi*16));
        accA[m] = MFMA32(vf, pbA[ks], accA[m]);   // V-frag read once, used twice
        accB[m] = MFMA32(vf, pbB[ks], accB[m]);
      }
    __builtin_amdgcn_s_setprio(0);
    // T4 counted wait: tile i+1's 4 loads are the oldest; only i+2's 4 may remain
    if (i + 1 < NT) {
      if (i + 2 < NT) { asm volatile("s_waitcnt vmcnt(4)" ::: "memory"); }
      else            { asm volatile("s_waitcnt vmcnt(0)" ::: "memory"); }
      __builtin_amdgcn_s_barrier();
      __builtin_amdgcn_sched_barrier(0);
    }
    rd  = (rd  == 2) ? 0 : rd + 1;
    wr2 = (wr2 == 2) ? 0 : wr2 + 1;
  }
#undef STAGE
  // ---- epilogue: unnormalized bf16 O^T partials + per-q partial sums ----
  psA += __shfl_xor(psA, 32, 64);
  psB += __shfl_xor(psB, 32, 64);
  u16* oA = opart + (((size_t)zkv*4 + b)*2048 + q0 + l31)*512 + h*64;
  u16* oB = oA + (size_t)32*512;
  #pragma unroll
  for (int m = 0; m < 2; ++m)
    #pragma unroll
    for (int rq = 0; rq < 4; ++rq) {
      u16x4 hA, hB;
      #pragma unroll
      for (int e = 0; e < 4; ++e) {
        hA[e] = f2bf(accA[m][rq*4 + e]);
        hB[e] = f2bf(accB[m][rq*4 + e]);
      }
      *(u16x4*)(oA + m*32 + rq*8 + hi*4) = hA;
      *(u16x4*)(oB + m*32 + rq*8 + hi*4) = hB;
    }
  if (hi == 0) {
    psb[((size_t)zkv*32 + bh)*2048 + q0 + l31]      = psA;
    psb[((size_t)zkv*32 + bh)*2048 + q0 + 32 + l31] = psB;
  }
}

// ---------------- LN0 fused with 2-way combine + q residual (bf16 partials) ------------
__global__ __launch_bounds__(256) void ln0c_k(
    const u16* __restrict__ opart, const float* __restrict__ psb,
    const u16* __restrict__ qb, const float* __restrict__ gam,
    const float* __restrict__ bet, u16* __restrict__ yh)
{
  int t = threadIdx.x, lane = t & 63, w = t >> 6;
  size_t row = (size_t)blockIdx.x * 4 + w;           // = b*2048 + q
  int b = (int)(row >> 11), q = (int)(row & 2047);
  int head = lane >> 3;                              // 8 lanes per 64-col head
  float sa = psb[((size_t)b*8 + head)*2048 + q] +
             psb[((size_t)32 + b*8 + head)*2048 + q];
  float inv = 1.0f / sa;
  const u16* xa = opart + row*512 + lane*8;
  const u16* xb = xa + (size_t)8192*512;
  u16x8 av  = *(const u16x8*)xa;
  u16x8 bv8 = *(const u16x8*)xb;
  u16x8 qr  = *(const u16x8*)(qb + row*512 + lane*8);
  float v[8];
  #pragma unroll
  for (int j = 0; j < 8; ++j)
    v[j] = (bf2f(av[j]) + bf2f(bv8[j]))*inv + bf2f(qr[j])*UNSCALE;
  float s = 0.0f, ss = 0.0f;
  #pragma unroll
  for (int j = 0; j < 8; ++j) { s += v[j]; ss += v[j]*v[j]; }
  #pragma unroll
  for (int m = 1; m < 64; m <<= 1) { s += __shfl_xor(s, m, 64); ss += __shfl_xor(ss, m, 64); }
  float mu = s * (1.0f/512.0f);
  float var = ss * (1.0f/512.0f) - mu*mu;
  float rs = rsqrtf(var + 1e-5f);
  const float* gp = gam + lane*8;
  const float* bp = bet + lane*8;
  f32x4 g0 = *(const f32x4*)gp, g1 = *(const f32x4*)(gp + 4);
  f32x4 be0 = *(const f32x4*)bp, be1 = *(const f32x4*)(bp + 4);
  u16x8 hv;
  #pragma unroll
  for (int j = 0; j < 4; ++j) {
    hv[j]   = f2bf((v[j]   - mu)*rs*g0[j] + be0[j]);
    hv[j+4] = f2bf((v[j+4] - mu)*rs*g1[j] + be1[j]);
  }
  *(u16x8*)(yh + row*512 + lane*8) = hv;
}

// ---------------- final LayerNorm (bf16 in, fp32 out) ----------------
__global__ __launch_bounds__(256) void ln_k(
    const u16* __restrict__ x, const float* __restrict__ gam,
    const float* __restrict__ bet, float* __restrict__ y)
{
  int t = threadIdx.x, lane = t & 63, w = t >> 6;
  size_t row = (size_t)blockIdx.x * 4 + w;
  u16x8 xv = *(const u16x8*)(x + row*512 + lane*8);
  float v[8];
  #pragma unroll
  for (int j = 0; j < 8; ++j) v[j] = bf2f(xv[j]);
  float s = 0.0f, ss = 0.0f;
  #pragma unroll
  for (int j = 0; j < 8; ++j) { s += v[j]; ss += v[j]*v[j]; }
  #pragma unroll
  for (int m = 1; m < 64; m <<= 1) { s += __shfl_xor(s, m, 64); ss += __shfl_xor(ss, m, 64); }
  float mu = s * (1.0f/512.0f);
  float var = ss * (1.0f/512.0f) - mu*mu;
  float rs = rsqrtf(var + 1e-5f);
  const float* gp = gam + lane*8;
  const float* bp = bet + lane*8;
  f32x4 g0 = *(const f32x4*)gp, g1 = *(const f32x4*)(gp + 4);
  f32x4 b0 = *(const f32x4*)bp, b1 = *(const f32x4*)(bp + 4);
  f32x4 o0, o1;
  #pragma unroll
  for (int j = 0; j < 4; ++j) {
    o0[j] = (v[j]   - mu)*rs*g0[j] + b0[j];
    o1[j] = (v[j+4] - mu)*rs*g1[j] + b1[j];
  }
  float* yp = y + row*512 + lane*8;
  *(f32x4*)yp = o0;
  *(f32x4*)(yp + 4) = o1;
}

extern "C" void kernel_launch(void* const* d_in, const int* in_sizes, int n_in,
                              void* d_out, int out_size, void* d_ws, size_t ws_size,
                              hipStream_t stream)
{
  const float* Q   = (const float*)d_in[0];
  const float* K   = (const float*)d_in[1];
  const float* Wq  = (const float*)d_in[2];
  const float* bq  = (const float*)d_in[3];
  const float* Wk  = (const float*)d_in[4];
  const float* bk  = (const float*)d_in[5];
  const float* Wv  = (const float*)d_in[6];
  const float* bv  = (const float*)d_in[7];
  const float* Wo  = (const float*)d_in[8];
  const float* bo  = (const float*)d_in[9];
  const float* g0  = (const float*)d_in[10];
  const float* b0  = (const float*)d_in[11];
  const float* g1  = (const float*)d_in[12];
  const float* b1  = (const float*)d_in[13];

  char* ws = (char*)d_ws;
  // layout (MB): wt 0-2 | qbuf 2-10 | kbuf 10-18 (Hbuf alias after attn) | vt 18-26 |
  //              opart 26-42 (bf16, 2 splits x 8MB) | psb 58-58.5 | Gb 59-67.4 (bf16)
  u16*   wt    = (u16*)(ws + 0);
  u16*   qbuf  = (u16*)(ws + (2u<<20));
  u16*   kbuf  = (u16*)(ws + (10u<<20));
  u16*   vt    = (u16*)(ws + (18u<<20));
  u16*   opart = (u16*)(ws + (26u<<20));
  float* psb   = (float*)(ws + (58u<<20));
  u16*   Gb    = (u16*)(ws + (59u<<20));
  u16*   Hbuf  = (u16*)(ws + (10u<<20));    // aliases kbuf (dead after attn)

  // 1. weight transpose+convert (Wq/bq scaled by 1/sqrt(512)*log2e)
  wprep_k<<<dim3(8, 8, 4), 256, 0, stream>>>(Wq, Wk, Wv, Wo, wt);
  // 2. all three projections; V written pre-transposed
  proj3_k<<<dim3(128, 4, 3), 512, 0, stream>>>(Q, K, wt, bq, bk, bv, qbuf, kbuf, vt);
  // 3. attention, q=64/wave, P-in-register, ring prefetch, KV-split x2 -> bf16 partials
  attn_k<<<dim3(8, 32, 2), 256, 0, stream>>>(qbuf, kbuf, vt, opart, psb);
  // 4. combine + q residual + LN0 -> Hbuf (bf16)
  ln0c_k<<<2048, 256, 0, stream>>>(opart, psb, qbuf, g0, b0, Hbuf);
  // 5. G = bf16(H + relu(H @ Wo + bo)) -> Gb
  gemmo_k<<<dim3(128, 4), 512, 0, stream>>>(Hbuf, wt + 3*262144, bo, Gb, Hbuf);
  // 6. LN1 -> out
  ln_k<<<2048, 256, 0, stream>>>(Gb, g1, b1, (float*)d_out);
}

// Round 11
// 100.236 us; speedup vs baseline: 2.3171x; 1.0077x over previous
//
#include <hip/hip_runtime.h>

typedef float f32x4 __attribute__((ext_vector_type(4)));
typedef float f32x16 __attribute__((ext_vector_type(16)));
typedef __bf16 bf16x8 __attribute__((ext_vector_type(8)));
typedef unsigned short u16;
typedef unsigned int u32;
typedef u16 u16x8 __attribute__((ext_vector_type(8)));
typedef u16 u16x4 __attribute__((ext_vector_type(4)));
typedef u32 u32x4 __attribute__((ext_vector_type(4)));

#define SCALE2F (0.044194173824159216f * 1.4426950408889634f)   // 1/sqrt(512) * log2(e)
#define UNSCALE (1.0f / SCALE2F)

__device__ __forceinline__ u16 f2bf(float x){ return __builtin_bit_cast(u16, (__bf16)x); }
__device__ __forceinline__ float bf2f(u16 h){ unsigned u = ((unsigned)h) << 16; return __builtin_bit_cast(float, u); }
// XOR swizzle within a 128B row: involution, bijective per 128B wrap
__device__ __forceinline__ int swz(int r, int byteInRow){ return (r*128 + byteInRow) ^ ((r & 7) << 4); }
// async global->LDS, 16B per lane; LDS dest must be wave-uniform base + lane*16
__device__ __forceinline__ void gload16(const void* g, void* l) {
  __builtin_amdgcn_global_load_lds(
      (const __attribute__((address_space(1))) void*)g,
      (__attribute__((address_space(3))) void*)l, 16, 0, 0);
}
__device__ __forceinline__ u32 cvtpk(float lo, float hi_) {
  u32 r;
  asm("v_cvt_pk_bf16_f32 %0, %1, %2" : "=v"(r) : "v"(lo), "v"(hi_));
  return r;
}
// v_permlane32_swap_b32: a' = {a.lo32, b.lo32}, b' = {a.hi32, b.hi32}
__device__ __forceinline__ void swap32(u32 &a, u32 &b) {
  asm("v_permlane32_swap_b32 %0, %1" : "+v"(a), "+v"(b));
}

#define MFMA(a,b,c)   __builtin_amdgcn_mfma_f32_16x16x32_bf16((a),(b),(c),0,0,0)
#define MFMA32(a,b,c) __builtin_amdgcn_mfma_f32_32x32x16_bf16((a),(b),(c),0,0,0)

// ---------------- weight prep: Wt[n][k] = bf16(W[k][n] * sc), 512x512 x4 ----------------
__global__ __launch_bounds__(256) void wprep_k(
    const float* __restrict__ W0, const float* __restrict__ W1,
    const float* __restrict__ W2, const float* __restrict__ W3,
    u16* __restrict__ wt)
{
  __shared__ float tile[64][68];
  const float* Ws[4] = {W0, W1, W2, W3};
  const float* W = Ws[blockIdx.z];
  const float sc = (blockIdx.z == 0) ? SCALE2F : 1.0f;   // fold softmax scale into Wq
  u16* out = wt + (size_t)blockIdx.z * 512 * 512;
  int k0 = blockIdx.x * 64, n0 = blockIdx.y * 64;
  int t = threadIdx.x;
  #pragma unroll
  for (int i = 0; i < 2; ++i) {
    int c = t + i*256; int r = c >> 3, k8 = c & 7;
    const float* src = W + (size_t)(k0 + r)*512 + n0 + k8*8;
    *(f32x4*)&tile[r][k8*8]     = *(const f32x4*)src;
    *(f32x4*)&tile[r][k8*8 + 4] = *(const f32x4*)(src + 4);
  }
  __syncthreads();
  #pragma unroll
  for (int i = 0; i < 2; ++i) {
    int c = t + i*256; int r = c >> 3, k8 = c & 7;
    u16x8 h;
    #pragma unroll
    for (int j = 0; j < 8; ++j) h[j] = f2bf(tile[k8*8 + j][r] * sc);
    *(u16x8*)(out + (size_t)(n0 + r)*512 + k0 + k8*8) = h;
  }
}

// ---------------- fused projections: z=0 Q->qbuf, z=1 K->kbuf, z=2 V->vt (transposed) ----
__global__ __launch_bounds__(512) void proj3_k(
    const float* __restrict__ Qin, const float* __restrict__ Kin,
    const u16* __restrict__ wt,
    const float* __restrict__ bq, const float* __restrict__ bk, const float* __restrict__ bv,
    u16* __restrict__ qbuf, u16* __restrict__ kbuf, u16* __restrict__ vt)
{
  __shared__ __align__(16) u16 lA[2][64*64];    // 8KB each
  __shared__ __align__(16) u16 lB[2][128*64];   // 16KB each
  int z = blockIdx.z;
  const float* A    = (z == 0) ? Qin : Kin;
  const u16*   Bt   = wt + (size_t)z * 262144;
  const float* bias = (z == 0) ? bq : (z == 1) ? bk : bv;
  const float bscale = (z == 0) ? SCALE2F : 1.0f;
  int row0 = blockIdx.x * 64, col0 = blockIdx.y * 128;
  int t = threadIdx.x, lane = t & 63, wid = t >> 6;
  int wr = wid >> 2, wc = wid & 3;              // 2x4 waves, 32x32 out each
  int l15 = lane & 15, lg = lane >> 4;
  int ar = t >> 3, ak8 = t & 7;
  int br = t >> 3;
  int bsrc = (((t & 7) << 4) ^ ((br & 7) << 4)) >> 1;
  const float* Arow = A + (size_t)row0 * 512;
  const u16*   Brow = Bt + (size_t)col0 * 512;

  f32x4 acc[2][2] = {};

  #pragma unroll
  for (int i = 0; i < 2; ++i)
    gload16(Brow + (size_t)(br + i*64)*512 + bsrc, (char*)lB[0] + i*8192 + t*16);
  {
    const float* src = Arow + (size_t)ar*512 + ak8*8;
    f32x4 x0 = *(const f32x4*)src;
    f32x4 x1 = *(const f32x4*)(src + 4);
    u16x8 h;
    #pragma unroll
    for (int j = 0; j < 4; ++j) { h[j] = f2bf(x0[j]); h[j+4] = f2bf(x1[j]); }
    *(u16x8*)((char*)lA[0] + swz(ar, ak8*16)) = h;
  }
  __syncthreads();

  int cur = 0;
  for (int k0 = 0; k0 < 512; k0 += 64) {
    bool pf = (k0 + 64 < 512);
    f32x4 px0, px1;
    if (pf) {
      #pragma unroll
      for (int i = 0; i < 2; ++i)
        gload16(Brow + (size_t)(br + i*64)*512 + k0 + 64 + bsrc, (char*)lB[cur^1] + i*8192 + t*16);
      const float* src = Arow + (size_t)ar*512 + k0 + 64 + ak8*8;
      px0 = *(const f32x4*)src;
      px1 = *(const f32x4*)(src + 4);
    }
    const char* lAc = (const char*)lA[cur];
    const char* lBc = (const char*)lB[cur];
    #pragma unroll
    for (int ks = 0; ks < 2; ++ks) {
      bf16x8 af[2], bfv[2];
      #pragma unroll
      for (int m = 0; m < 2; ++m)
        af[m] = *(const bf16x8*)(lAc + swz(wr*32 + m*16 + l15, ks*64 + lg*16));
      #pragma unroll
      for (int n = 0; n < 2; ++n)
        bfv[n] = *(const bf16x8*)(lBc + swz(wc*32 + n*16 + l15, ks*64 + lg*16));
      #pragma unroll
      for (int m = 0; m < 2; ++m)
        #pragma unroll
        for (int n = 0; n < 2; ++n)
          acc[m][n] = MFMA(af[m], bfv[n], acc[m][n]);
    }
    if (pf) {
      u16x8 h;
      #pragma unroll
      for (int j = 0; j < 4; ++j) { h[j] = f2bf(px0[j]); h[j+4] = f2bf(px1[j]); }
      *(u16x8*)((char*)lA[cur^1] + swz(ar, ak8*16)) = h;
    }
    __syncthreads();
    cur ^= 1;
  }

  if (z < 2) {
    u16* out = z ? kbuf : qbuf;
    #pragma unroll
    for (int m = 0; m < 2; ++m) {
      int rowg = row0 + wr*32 + m*16 + lg*4;
      #pragma unroll
      for (int n = 0; n < 2; ++n) {
        int colg = col0 + wc*32 + n*16 + l15;
        float bvv = bias[colg] * bscale;
        #pragma unroll
        for (int r = 0; r < 4; ++r)
          out[(size_t)(rowg + r)*512 + colg] = f2bf(acc[m][n][r] + bvv);
      }
    }
  } else {     // V: write transposed vt[b][dh][tok]
    #pragma unroll
    for (int m = 0; m < 2; ++m) {
      int rowg = row0 + wr*32 + m*16 + lg*4;
      int b = rowg >> 11, ntok = rowg & 2047;
      #pragma unroll
      for (int n = 0; n < 2; ++n) {
        int colg = col0 + wc*32 + n*16 + l15;
        float bvv = bias[colg];
        u16x4 hv;
        #pragma unroll
        for (int r = 0; r < 4; ++r) hv[r] = f2bf(acc[m][n][r] + bvv);
        *(u16x4*)(vt + ((size_t)b*512 + colg)*2048 + ntok) = hv;
      }
    }
  }
}

// ---------------- Wo GEMM: G = bf16( resid + relu(H @ Wo^T + bo) ), 64x128 tile --------
__global__ __launch_bounds__(512) void gemmo_k(
    const u16* __restrict__ A, const u16* __restrict__ Bt,
    const float* __restrict__ bias, u16* __restrict__ outb,
    const u16* __restrict__ resid)
{
  __shared__ __align__(16) u16 lA[2][64*64];
  __shared__ __align__(16) u16 lB[2][128*64];
  int row0 = blockIdx.x * 64, col0 = blockIdx.y * 128;
  int t = threadIdx.x, lane = t & 63, wid = t >> 6;
  int wr = wid >> 2, wc = wid & 3;
  int l15 = lane & 15, lg = lane >> 4;
  int ar = t >> 3;
  int asrc = (((t & 7) << 4) ^ ((ar & 7) << 4)) >> 1;
  const u16* Arow = A + (size_t)row0 * 512;
  const u16* Brow = Bt + (size_t)col0 * 512;
  f32x4 acc[2][2] = {};

  gload16(Arow + (size_t)ar*512 + asrc, (char*)lA[0] + t*16);
  #pragma unroll
  for (int i = 0; i < 2; ++i)
    gload16(Brow + (size_t)(ar + i*64)*512 + asrc, (char*)lB[0] + i*8192 + t*16);
  __syncthreads();

  int cur = 0;
  for (int k0 = 0; k0 < 512; k0 += 64) {
    if (k0 + 64 < 512) {
      gload16(Arow + (size_t)ar*512 + k0 + 64 + asrc, (char*)lA[cur^1] + t*16);
      #pragma unroll
      for (int i = 0; i < 2; ++i)
        gload16(Brow + (size_t)(ar + i*64)*512 + k0 + 64 + asrc, (char*)lB[cur^1] + i*8192 + t*16);
    }
    const char* lAc = (const char*)lA[cur];
    const char* lBc = (const char*)lB[cur];
    #pragma unroll
    for (int ks = 0; ks < 2; ++ks) {
      bf16x8 af[2], bfv[2];
      #pragma unroll
      for (int m = 0; m < 2; ++m)
        af[m] = *(const bf16x8*)(lAc + swz(wr*32 + m*16 + l15, ks*64 + lg*16));
      #pragma unroll
      for (int n = 0; n < 2; ++n)
        bfv[n] = *(const bf16x8*)(lBc + swz(wc*32 + n*16 + l15, ks*64 + lg*16));
      #pragma unroll
      for (int m = 0; m < 2; ++m)
        #pragma unroll
        for (int n = 0; n < 2; ++n)
          acc[m][n] = MFMA(af[m], bfv[n], acc[m][n]);
    }
    __syncthreads();
    cur ^= 1;
  }
  #pragma unroll
  for (int m = 0; m < 2; ++m) {
    int rowg = row0 + wr*32 + m*16 + lg*4;
    #pragma unroll
    for (int n = 0; n < 2; ++n) {
      int colg = col0 + wc*32 + n*16 + l15;
      float bvv = bias[colg];
      #pragma unroll
      for (int r = 0; r < 4; ++r) {
        size_t idx = (size_t)(rowg + r)*512 + colg;
        outb[idx] = f2bf(bf2f(resid[idx]) + fmaxf(acc[m][n][r] + bvv, 0.0f));
      }
    }
  }
}

// ---------------- flash attention: 32x32 MFMA, q=32/wave, 8 waves, 4 waves/SIMD ---------
// Register diet vs r7-r10 (q=64/wave, ~164 unified regs -> 2 waves/SIMD bracket):
// q=32/wave cuts acc to 32 + aq 16 + pb 16 (~105 unified) -> <=128 bracket -> 4 waves/SIMD.
// ps accumulated as a TREE (serial 64-add chain at 4cyc = ~256cyc/tile removed).
__device__ __forceinline__ void mk_pb(const f32x16& s, float& ps, bf16x8& f0, bf16x8& f1) {
  float p[16];
  #pragma unroll
  for (int r = 0; r < 16; ++r) p[r] = __builtin_amdgcn_exp2f(s[r]);
  float t0 = (p[0] + p[1])  + (p[2] + p[3]);
  float t1 = (p[4] + p[5])  + (p[6] + p[7]);
  float t2 = (p[8] + p[9])  + (p[10] + p[11]);
  float t3 = (p[12] + p[13]) + (p[14] + p[15]);
  ps += (t0 + t1) + (t2 + t3);
  u32 a0 = cvtpk(p[0],  p[1]),  b0 = cvtpk(p[4],  p[5]);
  u32 a1 = cvtpk(p[2],  p[3]),  b1 = cvtpk(p[6],  p[7]);
  swap32(a0, b0); swap32(a1, b1);
  u32 a2 = cvtpk(p[8],  p[9]),  b2 = cvtpk(p[12], p[13]);
  u32 a3 = cvtpk(p[10], p[11]), b3 = cvtpk(p[14], p[15]);
  swap32(a2, b2); swap32(a3, b3);
  u32x4 w0 = {a0, a1, b0, b1};   // kv slice +0..15 : words (0,1),(2,3),(4,5),(6,7)
  u32x4 w1 = {a2, a3, b2, b3};   // kv slice +16..31
  f0 = __builtin_bit_cast(bf16x8, w0);
  f1 = __builtin_bit_cast(bf16x8, w1);
}

__global__ __launch_bounds__(512, 4) void attn_k(
    const u16* __restrict__ qb, const u16* __restrict__ kb,
    const u16* __restrict__ vt, u16* __restrict__ opart, float* __restrict__ psb)
{
  __shared__ __align__(16) u16 lK[2][64*64];   // [kv][dh], 8KB each, swizzled reads
  __shared__ __align__(16) u16 lV[2][64*64];   // [dh][kv] (V^T), swizzled reads

  int t = threadIdx.x, lane = t & 63, wid = t >> 6;
  int bh = blockIdx.y, b = bh >> 3, h = bh & 7;
  int zkv = blockIdx.z;
  int kvbeg = zkv * 1024;                      // 2-way KV split, 16 tiles each
  int q0 = blockIdx.x * 256 + wid * 32;        // 8 waves x 32 q-rows
  int l31 = lane & 31, hi = lane >> 5;

  const u16* kbase = kb + ((size_t)b*2048)*512 + h*64;
  const u16* vbase = vt + ((size_t)b*512 + h*64)*2048;

  // staging: 512 thr x 16B = 8KB per issue; 1 K + 1 V gload16 per thread per tile
  int sr = t >> 3;                                   // 0..63
  int ssrc = ((t & 7) ^ (sr & 7)) << 3;              // inverse-swizzled src col (elements)

#define STAGE(buf, kvoff)                                                        \
  gload16(kbase + (size_t)((kvoff) + sr)*512 + ssrc, (char*)lK[buf] + t*16);     \
  gload16(vbase + (size_t)sr*2048 + (kvoff) + ssrc,  (char*)lV[buf] + t*16);

  // Q as B-operand: col q = l31, k = ks*16 + hi*8 + j
  bf16x8 aq[4];
  {
    const u16* qp = qb + ((size_t)(b*2048 + q0 + l31))*512 + h*64 + hi*8;
    #pragma unroll
    for (int ks = 0; ks < 4; ++ks) aq[ks] = *(const bf16x8*)(qp + ks*16);
  }

  f32x16 acc[2] = {};
  float ps = 0.0f;

  STAGE(0, kvbeg);
  __syncthreads();

  int cur = 0;
  for (int t0 = kvbeg; t0 < kvbeg + 1024; t0 += 64) {
    if (t0 + 64 < kvbeg + 1024) { STAGE(cur^1, t0 + 64); }
    const char* lKc = (const char*)lK[cur];
    const char* lVc = (const char*)lV[cur];
    bf16x8 pb[4];
    #pragma unroll
    for (int n = 0; n < 2; ++n) {
      f32x16 s = {};
      #pragma unroll
      for (int ks = 0; ks < 4; ++ks) {
        bf16x8 kf = *(const bf16x8*)(lKc + swz(n*32 + l31, ks*32 + hi*16));
        s = MFMA32(kf, aq[ks], s);
      }
      mk_pb(s, ps, pb[2*n], pb[2*n+1]);
    }
    #pragma unroll
    for (int m = 0; m < 2; ++m)
      #pragma unroll
      for (int ks = 0; ks < 4; ++ks) {
        bf16x8 vf = *(const bf16x8*)(lVc + swz(m*32 + l31, ks*32 + hi*16));
        acc[m] = MFMA32(vf, pb[ks], acc[m]);
      }
    __syncthreads();
    cur ^= 1;
  }
#undef STAGE
  // ---- epilogue: unnormalized bf16 O^T partials + per-q partial sums ----
  ps += __shfl_xor(ps, 32, 64);
  u16* oA = opart + (((size_t)zkv*4 + b)*2048 + q0 + l31)*512 + h*64;
  #pragma unroll
  for (int m = 0; m < 2; ++m)
    #pragma unroll
    for (int rq = 0; rq < 4; ++rq) {
      u16x4 hA;
      #pragma unroll
      for (int e = 0; e < 4; ++e) hA[e] = f2bf(acc[m][rq*4 + e]);
      *(u16x4*)(oA + m*32 + rq*8 + hi*4) = hA;
    }
  if (hi == 0)
    psb[((size_t)zkv*32 + bh)*2048 + q0 + l31] = ps;
}

// ---------------- LN0 fused with 2-way combine + q residual (bf16 partials) ------------
__global__ __launch_bounds__(256) void ln0c_k(
    const u16* __restrict__ opart, const float* __restrict__ psb,
    const u16* __restrict__ qb, const float* __restrict__ gam,
    const float* __restrict__ bet, u16* __restrict__ yh)
{
  int t = threadIdx.x, lane = t & 63, w = t >> 6;
  size_t row = (size_t)blockIdx.x * 4 + w;           // = b*2048 + q
  int b = (int)(row >> 11), q = (int)(row & 2047);
  int head = lane >> 3;                              // 8 lanes per 64-col head
  float sa = psb[((size_t)b*8 + head)*2048 + q] +
             psb[((size_t)32 + b*8 + head)*2048 + q];
  float inv = 1.0f / sa;
  const u16* xa = opart + row*512 + lane*8;
  const u16* xb = xa + (size_t)8192*512;
  u16x8 av  = *(const u16x8*)xa;
  u16x8 bv8 = *(const u16x8*)xb;
  u16x8 qr  = *(const u16x8*)(qb + row*512 + lane*8);
  float v[8];
  #pragma unroll
  for (int j = 0; j < 8; ++j)
    v[j] = (bf2f(av[j]) + bf2f(bv8[j]))*inv + bf2f(qr[j])*UNSCALE;
  float s = 0.0f, ss = 0.0f;
  #pragma unroll
  for (int j = 0; j < 8; ++j) { s += v[j]; ss += v[j]*v[j]; }
  #pragma unroll
  for (int m = 1; m < 64; m <<= 1) { s += __shfl_xor(s, m, 64); ss += __shfl_xor(ss, m, 64); }
  float mu = s * (1.0f/512.0f);
  float var = ss * (1.0f/512.0f) - mu*mu;
  float rs = rsqrtf(var + 1e-5f);
  const float* gp = gam + lane*8;
  const float* bp = bet + lane*8;
  f32x4 g0 = *(const f32x4*)gp, g1 = *(const f32x4*)(gp + 4);
  f32x4 be0 = *(const f32x4*)bp, be1 = *(const f32x4*)(bp + 4);
  u16x8 hv;
  #pragma unroll
  for (int j = 0; j < 4; ++j) {
    hv[j]   = f2bf((v[j]   - mu)*rs*g0[j] + be0[j]);
    hv[j+4] = f2bf((v[j+4] - mu)*rs*g1[j] + be1[j]);
  }
  *(u16x8*)(yh + row*512 + lane*8) = hv;
}

// ---------------- final LayerNorm (bf16 in, fp32 out) ----------------
__global__ __launch_bounds__(256) void ln_k(
    const u16* __restrict__ x, const float* __restrict__ gam,
    const float* __restrict__ bet, float* __restrict__ y)
{
  int t = threadIdx.x, lane = t & 63, w = t >> 6;
  size_t row = (size_t)blockIdx.x * 4 + w;
  u16x8 xv = *(const u16x8*)(x + row*512 + lane*8);
  float v[8];
  #pragma unroll
  for (int j = 0; j < 8; ++j) v[j] = bf2f(xv[j]);
  float s = 0.0f, ss = 0.0f;
  #pragma unroll
  for (int j = 0; j < 8; ++j) { s += v[j]; ss += v[j]*v[j]; }
  #pragma unroll
  for (int m = 1; m < 64; m <<= 1) { s += __shfl_xor(s, m, 64); ss += __shfl_xor(ss, m, 64); }
  float mu = s * (1.0f/512.0f);
  float var = ss * (1.0f/512.0f) - mu*mu;
  float rs = rsqrtf(var + 1e-5f);
  const float* gp = gam + lane*8;
  const float* bp = bet + lane*8;
  f32x4 g0 = *(const f32x4*)gp, g1 = *(const f32x4*)(gp + 4);
  f32x4 b0 = *(const f32x4*)bp, b1 = *(const f32x4*)(bp + 4);
  f32x4 o0, o1;
  #pragma unroll
  for (int j = 0; j < 4; ++j) {
    o0[j] = (v[j]   - mu)*rs*g0[j] + b0[j];
    o1[j] = (v[j+4] - mu)*rs*g1[j] + b1[j];
  }
  float* yp = y + row*512 + lane*8;
  *(f32x4*)yp = o0;
  *(f32x4*)(yp + 4) = o1;
}

extern "C" void kernel_launch(void* const* d_in, const int* in_sizes, int n_in,
                              void* d_out, int out_size, void* d_ws, size_t ws_size,
                              hipStream_t stream)
{
  const float* Q   = (const float*)d_in[0];
  const float* K   = (const float*)d_in[1];
  const float* Wq  = (const float*)d_in[2];
  const float* bq  = (const float*)d_in[3];
  const float* Wk  = (const float*)d_in[4];
  const float* bk  = (const float*)d_in[5];
  const float* Wv  = (const float*)d_in[6];
  const float* bv  = (const float*)d_in[7];
  const float* Wo  = (const float*)d_in[8];
  const float* bo  = (const float*)d_in[9];
  const float* g0  = (const float*)d_in[10];
  const float* b0  = (const float*)d_in[11];
  const float* g1  = (const float*)d_in[12];
  const float* b1  = (const float*)d_in[13];

  char* ws = (char*)d_ws;
  // layout (MB): wt 0-2 | qbuf 2-10 | kbuf 10-18 (Hbuf alias after attn) | vt 18-26 |
  //              opart 26-42 (bf16, 2 splits x 8MB) | psb 58-58.5 | Gb 59-67.4 (bf16)
  u16*   wt    = (u16*)(ws + 0);
  u16*   qbuf  = (u16*)(ws + (2u<<20));
  u16*   kbuf  = (u16*)(ws + (10u<<20));
  u16*   vt    = (u16*)(ws + (18u<<20));
  u16*   opart = (u16*)(ws + (26u<<20));
  float* psb   = (float*)(ws + (58u<<20));
  u16*   Gb    = (u16*)(ws + (59u<<20));
  u16*   Hbuf  = (u16*)(ws + (10u<<20));    // aliases kbuf (dead after attn)

  // 1. weight transpose+convert (Wq/bq scaled by 1/sqrt(512)*log2e)
  wprep_k<<<dim3(8, 8, 4), 256, 0, stream>>>(Wq, Wk, Wv, Wo, wt);
  // 2. all three projections; V written pre-transposed
  proj3_k<<<dim3(128, 4, 3), 512, 0, stream>>>(Q, K, wt, bq, bk, bv, qbuf, kbuf, vt);
  // 3. attention, q=32/wave, 8 waves, 4 waves/SIMD, KV-split x2 -> bf16 partials
  attn_k<<<dim3(8, 32, 2), 512, 0, stream>>>(qbuf, kbuf, vt, opart, psb);
  // 4. combine + q residual + LN0 -> Hbuf (bf16)
  ln0c_k<<<2048, 256, 0, stream>>>(opart, psb, qbuf, g0, b0, Hbuf);
  // 5. G = bf16(H + relu(H @ Wo + bo)) -> Gb
  gemmo_k<<<dim3(128, 4), 512, 0, stream>>>(Hbuf, wt + 3*262144, bo, Gb, Hbuf);
  // 6. LN1 -> out
  ln_k<<<2048, 256, 0, stream>>>(Gb, g1, b1, (float*)d_out);
}

// Round 12
// 97.909 us; speedup vs baseline: 2.3722x; 1.0238x over previous
//
#include <hip/hip_runtime.h>

typedef float f32x4 __attribute__((ext_vector_type(4)));
typedef float f32x16 __attribute__((ext_vector_type(16)));
typedef __bf16 bf16x8 __attribute__((ext_vector_type(8)));
typedef unsigned short u16;
typedef unsigned int u32;
typedef u16 u16x8 __attribute__((ext_vector_type(8)));
typedef u16 u16x4 __attribute__((ext_vector_type(4)));
typedef u32 u32x4 __attribute__((ext_vector_type(4)));

#define SCALE2F (0.044194173824159216f * 1.4426950408889634f)   // 1/sqrt(512) * log2(e)
#define UNSCALE (1.0f / SCALE2F)

__device__ __forceinline__ u16 f2bf(float x){ return __builtin_bit_cast(u16, (__bf16)x); }
__device__ __forceinline__ float bf2f(u16 h){ unsigned u = ((unsigned)h) << 16; return __builtin_bit_cast(float, u); }
// XOR swizzle within a 128B row: involution, bijective per 128B wrap
__device__ __forceinline__ int swz(int r, int byteInRow){ return (r*128 + byteInRow) ^ ((r & 7) << 4); }
// async global->LDS, 16B per lane; LDS dest must be wave-uniform base + lane*16
__device__ __forceinline__ void gload16(const void* g, void* l) {
  __builtin_amdgcn_global_load_lds(
      (const __attribute__((address_space(1))) void*)g,
      (__attribute__((address_space(3))) void*)l, 16, 0, 0);
}
__device__ __forceinline__ u32 cvtpk(float lo, float hi_) {
  u32 r;
  asm("v_cvt_pk_bf16_f32 %0, %1, %2" : "=v"(r) : "v"(lo), "v"(hi_));
  return r;
}
// v_permlane32_swap_b32: a' = {a.lo32, b.lo32}, b' = {a.hi32, b.hi32}
__device__ __forceinline__ void swap32(u32 &a, u32 &b) {
  asm("v_permlane32_swap_b32 %0, %1" : "+v"(a), "+v"(b));
}

#define MFMA(a,b,c)   __builtin_amdgcn_mfma_f32_16x16x32_bf16((a),(b),(c),0,0,0)
#define MFMA32(a,b,c) __builtin_amdgcn_mfma_f32_32x32x16_bf16((a),(b),(c),0,0,0)

// ---------------- weight prep: Wt[n][k] = bf16(W[k][n] * sc), 512x512 x4 ----------------
__global__ __launch_bounds__(256) void wprep_k(
    const float* __restrict__ W0, const float* __restrict__ W1,
    const float* __restrict__ W2, const float* __restrict__ W3,
    u16* __restrict__ wt)
{
  __shared__ float tile[64][68];
  const float* Ws[4] = {W0, W1, W2, W3};
  const float* W = Ws[blockIdx.z];
  const float sc = (blockIdx.z == 0) ? SCALE2F : 1.0f;   // fold softmax scale into Wq
  u16* out = wt + (size_t)blockIdx.z * 512 * 512;
  int k0 = blockIdx.x * 64, n0 = blockIdx.y * 64;
  int t = threadIdx.x;
  #pragma unroll
  for (int i = 0; i < 2; ++i) {
    int c = t + i*256; int r = c >> 3, k8 = c & 7;
    const float* src = W + (size_t)(k0 + r)*512 + n0 + k8*8;
    *(f32x4*)&tile[r][k8*8]     = *(const f32x4*)src;
    *(f32x4*)&tile[r][k8*8 + 4] = *(const f32x4*)(src + 4);
  }
  __syncthreads();
  #pragma unroll
  for (int i = 0; i < 2; ++i) {
    int c = t + i*256; int r = c >> 3, k8 = c & 7;
    u16x8 h;
    #pragma unroll
    for (int j = 0; j < 8; ++j) h[j] = f2bf(tile[k8*8 + j][r] * sc);
    *(u16x8*)(out + (size_t)(n0 + r)*512 + k0 + k8*8) = h;
  }
}

// ---------------- projections: z=0 Q->qbuf; z=1 K->kbuf AND V->vt (A staged once) -------
__global__ __launch_bounds__(512) void proj2_k(
    const float* __restrict__ Qin, const float* __restrict__ Kin,
    const u16* __restrict__ wt,
    const float* __restrict__ bq, const float* __restrict__ bk, const float* __restrict__ bv,
    u16* __restrict__ qbuf, u16* __restrict__ kbuf, u16* __restrict__ vt)
{
  __shared__ __align__(16) u16 lA[2][64*64];     // 16KB
  __shared__ __align__(16) u16 lB0[2][128*64];   // 32KB
  __shared__ __align__(16) u16 lB1[2][128*64];   // 32KB  (used only by z=1)
  int z = blockIdx.z;
  const float* A     = z ? Kin : Qin;
  const u16*   Bt0   = wt + (size_t)(z ? 1 : 0) * 262144;
  const u16*   Bt1   = wt + (size_t)2 * 262144;
  const float* bias0 = z ? bk : bq;
  const float bscale = z ? 1.0f : SCALE2F;
  int row0 = blockIdx.x * 64, col0 = blockIdx.y * 128;
  int t = threadIdx.x, lane = t & 63, wid = t >> 6;
  int wr = wid >> 2, wc = wid & 3;              // 2x4 waves, 32x32 out each
  int l15 = lane & 15, lg = lane >> 4;
  int ar = t >> 3, ak8 = t & 7;
  int br = t >> 3;
  int bsrc = (((t & 7) << 4) ^ ((br & 7) << 4)) >> 1;
  const float* Arow = A + (size_t)row0 * 512;
  const u16*   B0row = Bt0 + (size_t)col0 * 512;
  const u16*   B1row = Bt1 + (size_t)col0 * 512;

  f32x4 acc0[2][2] = {}, acc1[2][2] = {};

  #pragma unroll
  for (int i = 0; i < 2; ++i)
    gload16(B0row + (size_t)(br + i*64)*512 + bsrc, (char*)lB0[0] + i*8192 + t*16);
  if (z) {
    #pragma unroll
    for (int i = 0; i < 2; ++i)
      gload16(B1row + (size_t)(br + i*64)*512 + bsrc, (char*)lB1[0] + i*8192 + t*16);
  }
  {
    const float* src = Arow + (size_t)ar*512 + ak8*8;
    f32x4 x0 = *(const f32x4*)src;
    f32x4 x1 = *(const f32x4*)(src + 4);
    u16x8 h;
    #pragma unroll
    for (int j = 0; j < 4; ++j) { h[j] = f2bf(x0[j]); h[j+4] = f2bf(x1[j]); }
    *(u16x8*)((char*)lA[0] + swz(ar, ak8*16)) = h;
  }
  __syncthreads();

  int cur = 0;
  for (int k0 = 0; k0 < 512; k0 += 64) {
    bool pf = (k0 + 64 < 512);
    f32x4 px0, px1;
    if (pf) {
      #pragma unroll
      for (int i = 0; i < 2; ++i)
        gload16(B0row + (size_t)(br + i*64)*512 + k0 + 64 + bsrc, (char*)lB0[cur^1] + i*8192 + t*16);
      if (z) {
        #pragma unroll
        for (int i = 0; i < 2; ++i)
          gload16(B1row + (size_t)(br + i*64)*512 + k0 + 64 + bsrc, (char*)lB1[cur^1] + i*8192 + t*16);
      }
      const float* src = Arow + (size_t)ar*512 + k0 + 64 + ak8*8;
      px0 = *(const f32x4*)src;
      px1 = *(const f32x4*)(src + 4);
    }
    const char* lAc = (const char*)lA[cur];
    const char* lB0c = (const char*)lB0[cur];
    const char* lB1c = (const char*)lB1[cur];
    #pragma unroll
    for (int ks = 0; ks < 2; ++ks) {
      bf16x8 af[2], b0f[2], b1f[2];
      #pragma unroll
      for (int m = 0; m < 2; ++m)
        af[m] = *(const bf16x8*)(lAc + swz(wr*32 + m*16 + l15, ks*64 + lg*16));
      #pragma unroll
      for (int n = 0; n < 2; ++n) {
        int rb = wc*32 + n*16 + l15;
        b0f[n] = *(const bf16x8*)(lB0c + swz(rb, ks*64 + lg*16));
        if (z) b1f[n] = *(const bf16x8*)(lB1c + swz(rb, ks*64 + lg*16));
      }
      #pragma unroll
      for (int m = 0; m < 2; ++m)
        #pragma unroll
        for (int n = 0; n < 2; ++n) {
          acc0[m][n] = MFMA(af[m], b0f[n], acc0[m][n]);
          if (z) acc1[m][n] = MFMA(af[m], b1f[n], acc1[m][n]);
        }
    }
    if (pf) {
      u16x8 h;
      #pragma unroll
      for (int j = 0; j < 4; ++j) { h[j] = f2bf(px0[j]); h[j+4] = f2bf(px1[j]); }
      *(u16x8*)((char*)lA[cur^1] + swz(ar, ak8*16)) = h;
    }
    __syncthreads();
    cur ^= 1;
  }

  // epilogue: acc0 -> qbuf (z=0) or kbuf (z=1); acc1 -> vt transposed (z=1 only)
  u16* out0 = z ? kbuf : qbuf;
  #pragma unroll
  for (int m = 0; m < 2; ++m) {
    int rowg = row0 + wr*32 + m*16 + lg*4;
    #pragma unroll
    for (int n = 0; n < 2; ++n) {
      int colg = col0 + wc*32 + n*16 + l15;
      float bvv = bias0[colg] * bscale;
      #pragma unroll
      for (int r = 0; r < 4; ++r)
        out0[(size_t)(rowg + r)*512 + colg] = f2bf(acc0[m][n][r] + bvv);
    }
  }
  if (z) {
    #pragma unroll
    for (int m = 0; m < 2; ++m) {
      int rowg = row0 + wr*32 + m*16 + lg*4;
      int b = rowg >> 11, ntok = rowg & 2047;
      #pragma unroll
      for (int n = 0; n < 2; ++n) {
        int colg = col0 + wc*32 + n*16 + l15;
        float bvv = bv[colg];
        u16x4 hv;
        #pragma unroll
        for (int r = 0; r < 4; ++r) hv[r] = f2bf(acc1[m][n][r] + bvv);
        *(u16x4*)(vt + ((size_t)b*512 + colg)*2048 + ntok) = hv;
      }
    }
  }
}

// ---------------- Wo GEMM: G = bf16( resid + relu(H @ Wo^T + bo) ), 64x128 tile --------
__global__ __launch_bounds__(512) void gemmo_k(
    const u16* __restrict__ A, const u16* __restrict__ Bt,
    const float* __restrict__ bias, u16* __restrict__ outb,
    const u16* __restrict__ resid)
{
  __shared__ __align__(16) u16 lA[2][64*64];
  __shared__ __align__(16) u16 lB[2][128*64];
  int row0 = blockIdx.x * 64, col0 = blockIdx.y * 128;
  int t = threadIdx.x, lane = t & 63, wid = t >> 6;
  int wr = wid >> 2, wc = wid & 3;
  int l15 = lane & 15, lg = lane >> 4;
  int ar = t >> 3;
  int asrc = (((t & 7) << 4) ^ ((ar & 7) << 4)) >> 1;
  const u16* Arow = A + (size_t)row0 * 512;
  const u16* Brow = Bt + (size_t)col0 * 512;
  f32x4 acc[2][2] = {};

  gload16(Arow + (size_t)ar*512 + asrc, (char*)lA[0] + t*16);
  #pragma unroll
  for (int i = 0; i < 2; ++i)
    gload16(Brow + (size_t)(ar + i*64)*512 + asrc, (char*)lB[0] + i*8192 + t*16);
  __syncthreads();

  int cur = 0;
  for (int k0 = 0; k0 < 512; k0 += 64) {
    if (k0 + 64 < 512) {
      gload16(Arow + (size_t)ar*512 + k0 + 64 + asrc, (char*)lA[cur^1] + t*16);
      #pragma unroll
      for (int i = 0; i < 2; ++i)
        gload16(Brow + (size_t)(ar + i*64)*512 + k0 + 64 + asrc, (char*)lB[cur^1] + i*8192 + t*16);
    }
    const char* lAc = (const char*)lA[cur];
    const char* lBc = (const char*)lB[cur];
    #pragma unroll
    for (int ks = 0; ks < 2; ++ks) {
      bf16x8 af[2], bfv[2];
      #pragma unroll
      for (int m = 0; m < 2; ++m)
        af[m] = *(const bf16x8*)(lAc + swz(wr*32 + m*16 + l15, ks*64 + lg*16));
      #pragma unroll
      for (int n = 0; n < 2; ++n)
        bfv[n] = *(const bf16x8*)(lBc + swz(wc*32 + n*16 + l15, ks*64 + lg*16));
      #pragma unroll
      for (int m = 0; m < 2; ++m)
        #pragma unroll
        for (int n = 0; n < 2; ++n)
          acc[m][n] = MFMA(af[m], bfv[n], acc[m][n]);
    }
    __syncthreads();
    cur ^= 1;
  }
  #pragma unroll
  for (int m = 0; m < 2; ++m) {
    int rowg = row0 + wr*32 + m*16 + lg*4;
    #pragma unroll
    for (int n = 0; n < 2; ++n) {
      int colg = col0 + wc*32 + n*16 + l15;
      float bvv = bias[colg];
      #pragma unroll
      for (int r = 0; r < 4; ++r) {
        size_t idx = (size_t)(rowg + r)*512 + colg;
        outb[idx] = f2bf(bf2f(resid[idx]) + fmaxf(acc[m][n][r] + bvv, 0.0f));
      }
    }
  }
}

// ---------------- flash attention: 8 waves = 4 q-waves x 2 KV-halves, in-block combine --
// Waves 0-3: kv 0..1023 for q-rows q0..q0+127; waves 4-7: kv 1024..2047 for SAME q-rows.
// After the loop, half-1 passes partial O^T + sums via LDS (reusing the dead K/V buffers);
// half-0 normalizes, adds q-residual, writes FINAL bf16 O. No opart/psb roundtrip.
__device__ __forceinline__ void mk_pb(const f32x16& s, float& ps, bf16x8& f0, bf16x8& f1) {
  float p[16];
  #pragma unroll
  for (int r = 0; r < 16; ++r) p[r] = __builtin_amdgcn_exp2f(s[r]);
  float t0 = (p[0] + p[1])  + (p[2] + p[3]);
  float t1 = (p[4] + p[5])  + (p[6] + p[7]);
  float t2 = (p[8] + p[9])  + (p[10] + p[11]);
  float t3 = (p[12] + p[13]) + (p[14] + p[15]);
  ps += (t0 + t1) + (t2 + t3);
  u32 a0 = cvtpk(p[0],  p[1]),  b0 = cvtpk(p[4],  p[5]);
  u32 a1 = cvtpk(p[2],  p[3]),  b1 = cvtpk(p[6],  p[7]);
  swap32(a0, b0); swap32(a1, b1);
  u32 a2 = cvtpk(p[8],  p[9]),  b2 = cvtpk(p[12], p[13]);
  u32 a3 = cvtpk(p[10], p[11]), b3 = cvtpk(p[14], p[15]);
  swap32(a2, b2); swap32(a3, b3);
  u32x4 w0 = {a0, a1, b0, b1};
  u32x4 w1 = {a2, a3, b2, b3};
  f0 = __builtin_bit_cast(bf16x8, w0);
  f1 = __builtin_bit_cast(bf16x8, w1);
}

__global__ __launch_bounds__(512, 4) void attn_k(
    const u16* __restrict__ qb, const u16* __restrict__ kb,
    const u16* __restrict__ vt, u16* __restrict__ ob)
{
  __shared__ __align__(16) char smem[65536];   // lK: 4x8KB | lV: 4x8KB; combine reuses lK

  int t = threadIdx.x, lane = t & 63, wid = t >> 6;
  int bh = blockIdx.y, b = bh >> 3, h = bh & 7;
  int half = wid >> 2;                         // KV half (0: 0-1023, 1: 1024-2047)
  int qw = wid & 3;
  int q0 = blockIdx.x * 128 + qw * 32;         // 4 q-waves x 32 rows
  int l31 = lane & 31, hi = lane >> 5;

  const u16* kbase = kb + ((size_t)b*2048)*512 + h*64;
  const u16* vbase = vt + ((size_t)b*512 + h*64)*2048;

  int sr = t >> 3;                                   // 0..63
  int ssrc = ((t & 7) ^ (sr & 7)) << 3;              // inverse-swizzled src col (elements)

  // lK buffer (half, buf) at smem + (half*2+buf)*8192; lV at +32768
#define LKB(hf, bf) (smem + ((hf)*2 + (bf))*8192)
#define LVB(hf, bf) (smem + 32768 + ((hf)*2 + (bf))*8192)
#define STAGE(buf, off)                                                           \
  gload16(kbase + (size_t)((off) + sr)*512 + ssrc,        LKB(0,buf) + t*16);     \
  gload16(kbase + (size_t)((off) + 1024 + sr)*512 + ssrc, LKB(1,buf) + t*16);     \
  gload16(vbase + (size_t)sr*2048 + (off) + ssrc,         LVB(0,buf) + t*16);     \
  gload16(vbase + (size_t)sr*2048 + (off) + 1024 + ssrc,  LVB(1,buf) + t*16);

  // Q as B-operand: col q = l31, k = ks*16 + hi*8 + j
  bf16x8 aq[4];
  {
    const u16* qp = qb + ((size_t)(b*2048 + q0 + l31))*512 + h*64 + hi*8;
    #pragma unroll
    for (int ks = 0; ks < 4; ++ks) aq[ks] = *(const bf16x8*)(qp + ks*16);
  }

  f32x16 acc[2] = {};
  float ps = 0.0f;

  STAGE(0, 0);
  __syncthreads();

  int cur = 0;
  for (int i = 0; i < 16; ++i) {
    if (i + 1 < 16) { STAGE(cur^1, (i+1)*64); }
    const char* lKc = LKB(half, cur);
    const char* lVc = LVB(half, cur);
    bf16x8 pb[4];
    #pragma unroll
    for (int n = 0; n < 2; ++n) {
      f32x16 s = {};
      #pragma unroll
      for (int ks = 0; ks < 4; ++ks) {
        bf16x8 kf = *(const bf16x8*)(lKc + swz(n*32 + l31, ks*32 + hi*16));
        s = MFMA32(kf, aq[ks], s);
      }
      mk_pb(s, ps, pb[2*n], pb[2*n+1]);
    }
    #pragma unroll
    for (int m = 0; m < 2; ++m)
      #pragma unroll
      for (int ks = 0; ks < 4; ++ks) {
        bf16x8 vf = *(const bf16x8*)(lVc + swz(m*32 + l31, ks*32 + hi*16));
        acc[m] = MFMA32(vf, pb[ks], acc[m]);
      }
    __syncthreads();   // also separates last compute from the combine-buffer reuse below
    cur ^= 1;
  }
#undef STAGE

  // ---- in-block combine: half-1 -> LDS (pitch 68 f32, region 2208 f32 per q-wave) ----
  ps += __shfl_xor(ps, 32, 64);
  float* cb = (float*)smem;
  if (half == 1) {
    float* dst = cb + qw * 2208;
    #pragma unroll
    for (int m = 0; m < 2; ++m)
      #pragma unroll
      for (int rq = 0; rq < 4; ++rq) {
        f32x4 v = {acc[m][rq*4], acc[m][rq*4+1], acc[m][rq*4+2], acc[m][rq*4+3]};
        *(f32x4*)(dst + l31*68 + m*32 + rq*8 + hi*4) = v;
      }
    if (hi == 0) dst[2176 + l31] = ps;
  }
  __syncthreads();
  if (half == 0) {
    const float* src = cb + qw * 2208;
    float inv = 1.0f / (ps + src[2176 + l31]);
    u16* obase = ob + ((size_t)(b*2048 + q0 + l31))*512 + h*64;
    const u16* qrb = qb + ((size_t)(b*2048 + q0 + l31))*512 + h*64;
    #pragma unroll
    for (int m = 0; m < 2; ++m)
      #pragma unroll
      for (int rq = 0; rq < 4; ++rq) {
        f32x4 other = *(const f32x4*)(src + l31*68 + m*32 + rq*8 + hi*4);
        u16x4 qr4 = *(const u16x4*)(qrb + m*32 + rq*8 + hi*4);
        u16x4 o4;
        #pragma unroll
        for (int e = 0; e < 4; ++e)
          o4[e] = f2bf((acc[m][rq*4 + e] + other[e])*inv + bf2f(qr4[e])*UNSCALE);
        *(u16x4*)(obase + m*32 + rq*8 + hi*4) = o4;
      }
  }
}

// ---------------- LayerNorm, bf16 in; OUT_BF16 selects bf16 or fp32 output --------------
template<int OUT_BF16>
__global__ __launch_bounds__(256) void ln_k(
    const u16* __restrict__ x, const float* __restrict__ gam,
    const float* __restrict__ bet, float* __restrict__ yf, u16* __restrict__ yh)
{
  int t = threadIdx.x, lane = t & 63, w = t >> 6;
  size_t row = (size_t)blockIdx.x * 4 + w;
  u16x8 xv = *(const u16x8*)(x + row*512 + lane*8);
  float v[8];
  #pragma unroll
  for (int j = 0; j < 8; ++j) v[j] = bf2f(xv[j]);
  float s = 0.0f, ss = 0.0f;
  #pragma unroll
  for (int j = 0; j < 8; ++j) { s += v[j]; ss += v[j]*v[j]; }
  #pragma unroll
  for (int m = 1; m < 64; m <<= 1) { s += __shfl_xor(s, m, 64); ss += __shfl_xor(ss, m, 64); }
  float mu = s * (1.0f/512.0f);
  float var = ss * (1.0f/512.0f) - mu*mu;
  float rs = rsqrtf(var + 1e-5f);
  const float* gp = gam + lane*8;
  const float* bp = bet + lane*8;
  f32x4 g0 = *(const f32x4*)gp, g1 = *(const f32x4*)(gp + 4);
  f32x4 b0 = *(const f32x4*)bp, b1 = *(const f32x4*)(bp + 4);
  if (OUT_BF16) {
    u16x8 hv;
    #pragma unroll
    for (int j = 0; j < 4; ++j) {
      hv[j]   = f2bf((v[j]   - mu)*rs*g0[j] + b0[j]);
      hv[j+4] = f2bf((v[j+4] - mu)*rs*g1[j] + b1[j]);
    }
    *(u16x8*)(yh + row*512 + lane*8) = hv;
  } else {
    f32x4 o0, o1;
    #pragma unroll
    for (int j = 0; j < 4; ++j) {
      o0[j] = (v[j]   - mu)*rs*g0[j] + b0[j];
      o1[j] = (v[j+4] - mu)*rs*g1[j] + b1[j];
    }
    float* yp = yf + row*512 + lane*8;
    *(f32x4*)yp = o0;
    *(f32x4*)(yp + 4) = o1;
  }
}

extern "C" void kernel_launch(void* const* d_in, const int* in_sizes, int n_in,
                              void* d_out, int out_size, void* d_ws, size_t ws_size,
                              hipStream_t stream)
{
  const float* Q   = (const float*)d_in[0];
  const float* K   = (const float*)d_in[1];
  const float* Wq  = (const float*)d_in[2];
  const float* bq  = (const float*)d_in[3];
  const float* Wk  = (const float*)d_in[4];
  const float* bk  = (const float*)d_in[5];
  const float* Wv  = (const float*)d_in[6];
  const float* bv  = (const float*)d_in[7];
  const float* Wo  = (const float*)d_in[8];
  const float* bo  = (const float*)d_in[9];
  const float* g0  = (const float*)d_in[10];
  const float* b0  = (const float*)d_in[11];
  const float* g1  = (const float*)d_in[12];
  const float* b1  = (const float*)d_in[13];

  char* ws = (char*)d_ws;
  // layout (MB): wt 0-2 | qbuf 2-10 | kbuf 10-18 | vt 18-26 | ob 26-34 | Hbuf 34-42 | Gb 42-50.4
  u16*   wt    = (u16*)(ws + 0);
  u16*   qbuf  = (u16*)(ws + (2u<<20));
  u16*   kbuf  = (u16*)(ws + (10u<<20));
  u16*   vt    = (u16*)(ws + (18u<<20));
  u16*   ob    = (u16*)(ws + (26u<<20));
  u16*   Hbuf  = (u16*)(ws + (34u<<20));
  u16*   Gb    = (u16*)(ws + (42u<<20));

  // 1. weight transpose+convert (Wq/bq scaled by 1/sqrt(512)*log2e)
  wprep_k<<<dim3(8, 8, 4), 256, 0, stream>>>(Wq, Wk, Wv, Wo, wt);
  // 2. projections: z=0 Q; z=1 K+V fused (K read once), V written pre-transposed
  proj2_k<<<dim3(128, 4, 2), 512, 0, stream>>>(Q, K, wt, bq, bk, bv, qbuf, kbuf, vt);
  // 3. attention, in-block KV-split + combine, residual added -> ob (bf16, final)
  attn_k<<<dim3(16, 32), 512, 0, stream>>>(qbuf, kbuf, vt, ob);
  // 4. LN0 -> Hbuf (bf16)
  ln_k<1><<<2048, 256, 0, stream>>>(ob, g0, b0, nullptr, Hbuf);
  // 5. G = bf16(H + relu(H @ Wo + bo)) -> Gb
  gemmo_k<<<dim3(128, 4), 512, 0, stream>>>(Hbuf, wt + 3*262144, bo, Gb, Hbuf);
  // 6. LN1 -> out (fp32)
  ln_k<0><<<2048, 256, 0, stream>>>(Gb, g1, b1, (float*)d_out, nullptr);
}

// Round 13
// 95.596 us; speedup vs baseline: 2.4296x; 1.0242x over previous
//
#include <hip/hip_runtime.h>

typedef float f32x4 __attribute__((ext_vector_type(4)));
typedef float f32x16 __attribute__((ext_vector_type(16)));
typedef __bf16 bf16x8 __attribute__((ext_vector_type(8)));
typedef unsigned short u16;
typedef unsigned int u32;
typedef u16 u16x8 __attribute__((ext_vector_type(8)));
typedef u16 u16x4 __attribute__((ext_vector_type(4)));
typedef u32 u32x4 __attribute__((ext_vector_type(4)));

#define SCALE2F (0.044194173824159216f * 1.4426950408889634f)   // 1/sqrt(512) * log2(e)
#define UNSCALE (1.0f / SCALE2F)

__device__ __forceinline__ u16 f2bf(float x){ return __builtin_bit_cast(u16, (__bf16)x); }
__device__ __forceinline__ float bf2f(u16 h){ unsigned u = ((unsigned)h) << 16; return __builtin_bit_cast(float, u); }
// XOR swizzle within a 128B row: involution, bijective per 128B wrap
__device__ __forceinline__ int swz(int r, int byteInRow){ return (r*128 + byteInRow) ^ ((r & 7) << 4); }
// async global->LDS, 16B per lane; LDS dest must be wave-uniform base + lane*16
__device__ __forceinline__ void gload16(const void* g, void* l) {
  __builtin_amdgcn_global_load_lds(
      (const __attribute__((address_space(1))) void*)g,
      (__attribute__((address_space(3))) void*)l, 16, 0, 0);
}
__device__ __forceinline__ u32 cvtpk(float lo, float hi_) {
  u32 r;
  asm("v_cvt_pk_bf16_f32 %0, %1, %2" : "=v"(r) : "v"(lo), "v"(hi_));
  return r;
}
// v_permlane32_swap_b32: a' = {a.lo32, b.lo32}, b' = {a.hi32, b.hi32}
__device__ __forceinline__ void swap32(u32 &a, u32 &b) {
  asm("v_permlane32_swap_b32 %0, %1" : "+v"(a), "+v"(b));
}

#define MFMA(a,b,c)   __builtin_amdgcn_mfma_f32_16x16x32_bf16((a),(b),(c),0,0,0)
#define MFMA32(a,b,c) __builtin_amdgcn_mfma_f32_32x32x16_bf16((a),(b),(c),0,0,0)

// ---------------- weight prep: Wt[n][k] = bf16(W[k][n] * sc), 512x512 x4 ----------------
__global__ __launch_bounds__(256) void wprep_k(
    const float* __restrict__ W0, const float* __restrict__ W1,
    const float* __restrict__ W2, const float* __restrict__ W3,
    u16* __restrict__ wt)
{
  __shared__ float tile[64][68];
  const float* Ws[4] = {W0, W1, W2, W3};
  const float* W = Ws[blockIdx.z];
  const float sc = (blockIdx.z == 0) ? SCALE2F : 1.0f;   // fold softmax scale into Wq
  u16* out = wt + (size_t)blockIdx.z * 512 * 512;
  int k0 = blockIdx.x * 64, n0 = blockIdx.y * 64;
  int t = threadIdx.x;
  #pragma unroll
  for (int i = 0; i < 2; ++i) {
    int c = t + i*256; int r = c >> 3, k8 = c & 7;
    const float* src = W + (size_t)(k0 + r)*512 + n0 + k8*8;
    *(f32x4*)&tile[r][k8*8]     = *(const f32x4*)src;
    *(f32x4*)&tile[r][k8*8 + 4] = *(const f32x4*)(src + 4);
  }
  __syncthreads();
  #pragma unroll
  for (int i = 0; i < 2; ++i) {
    int c = t + i*256; int r = c >> 3, k8 = c & 7;
    u16x8 h;
    #pragma unroll
    for (int j = 0; j < 8; ++j) h[j] = f2bf(tile[k8*8 + j][r] * sc);
    *(u16x8*)(out + (size_t)(n0 + r)*512 + k0 + k8*8) = h;
  }
}

// ---------------- projections: z=0 Q->qbuf; z=1 K->kbuf AND V->vt (A staged once) -------
__global__ __launch_bounds__(512) void proj2_k(
    const float* __restrict__ Qin, const float* __restrict__ Kin,
    const u16* __restrict__ wt,
    const float* __restrict__ bq, const float* __restrict__ bk, const float* __restrict__ bv,
    u16* __restrict__ qbuf, u16* __restrict__ kbuf, u16* __restrict__ vt)
{
  __shared__ __align__(16) u16 lA[2][64*64];     // 16KB
  __shared__ __align__(16) u16 lB0[2][128*64];   // 32KB
  __shared__ __align__(16) u16 lB1[2][128*64];   // 32KB  (used only by z=1)
  int z = blockIdx.z;
  const float* A     = z ? Kin : Qin;
  const u16*   Bt0   = wt + (size_t)(z ? 1 : 0) * 262144;
  const u16*   Bt1   = wt + (size_t)2 * 262144;
  const float* bias0 = z ? bk : bq;
  const float bscale = z ? 1.0f : SCALE2F;
  int row0 = blockIdx.x * 64, col0 = blockIdx.y * 128;
  int t = threadIdx.x, lane = t & 63, wid = t >> 6;
  int wr = wid >> 2, wc = wid & 3;              // 2x4 waves, 32x32 out each
  int l15 = lane & 15, lg = lane >> 4;
  int ar = t >> 3, ak8 = t & 7;
  int br = t >> 3;
  int bsrc = (((t & 7) << 4) ^ ((br & 7) << 4)) >> 1;
  const float* Arow = A + (size_t)row0 * 512;
  const u16*   B0row = Bt0 + (size_t)col0 * 512;
  const u16*   B1row = Bt1 + (size_t)col0 * 512;

  f32x4 acc0[2][2] = {}, acc1[2][2] = {};

  #pragma unroll
  for (int i = 0; i < 2; ++i)
    gload16(B0row + (size_t)(br + i*64)*512 + bsrc, (char*)lB0[0] + i*8192 + t*16);
  if (z) {
    #pragma unroll
    for (int i = 0; i < 2; ++i)
      gload16(B1row + (size_t)(br + i*64)*512 + bsrc, (char*)lB1[0] + i*8192 + t*16);
  }
  {
    const float* src = Arow + (size_t)ar*512 + ak8*8;
    f32x4 x0 = *(const f32x4*)src;
    f32x4 x1 = *(const f32x4*)(src + 4);
    u16x8 h;
    #pragma unroll
    for (int j = 0; j < 4; ++j) { h[j] = f2bf(x0[j]); h[j+4] = f2bf(x1[j]); }
    *(u16x8*)((char*)lA[0] + swz(ar, ak8*16)) = h;
  }
  __syncthreads();

  int cur = 0;
  for (int k0 = 0; k0 < 512; k0 += 64) {
    bool pf = (k0 + 64 < 512);
    f32x4 px0, px1;
    if (pf) {
      #pragma unroll
      for (int i = 0; i < 2; ++i)
        gload16(B0row + (size_t)(br + i*64)*512 + k0 + 64 + bsrc, (char*)lB0[cur^1] + i*8192 + t*16);
      if (z) {
        #pragma unroll
        for (int i = 0; i < 2; ++i)
          gload16(B1row + (size_t)(br + i*64)*512 + k0 + 64 + bsrc, (char*)lB1[cur^1] + i*8192 + t*16);
      }
      const float* src = Arow + (size_t)ar*512 + k0 + 64 + ak8*8;
      px0 = *(const f32x4*)src;
      px1 = *(const f32x4*)(src + 4);
    }
    const char* lAc = (const char*)lA[cur];
    const char* lB0c = (const char*)lB0[cur];
    const char* lB1c = (const char*)lB1[cur];
    #pragma unroll
    for (int ks = 0; ks < 2; ++ks) {
      bf16x8 af[2], b0f[2], b1f[2];
      #pragma unroll
      for (int m = 0; m < 2; ++m)
        af[m] = *(const bf16x8*)(lAc + swz(wr*32 + m*16 + l15, ks*64 + lg*16));
      #pragma unroll
      for (int n = 0; n < 2; ++n) {
        int rb = wc*32 + n*16 + l15;
        b0f[n] = *(const bf16x8*)(lB0c + swz(rb, ks*64 + lg*16));
        if (z) b1f[n] = *(const bf16x8*)(lB1c + swz(rb, ks*64 + lg*16));
      }
      #pragma unroll
      for (int m = 0; m < 2; ++m)
        #pragma unroll
        for (int n = 0; n < 2; ++n) {
          acc0[m][n] = MFMA(af[m], b0f[n], acc0[m][n]);
          if (z) acc1[m][n] = MFMA(af[m], b1f[n], acc1[m][n]);
        }
    }
    if (pf) {
      u16x8 h;
      #pragma unroll
      for (int j = 0; j < 4; ++j) { h[j] = f2bf(px0[j]); h[j+4] = f2bf(px1[j]); }
      *(u16x8*)((char*)lA[cur^1] + swz(ar, ak8*16)) = h;
    }
    __syncthreads();
    cur ^= 1;
  }

  // epilogue: acc0 -> qbuf (z=0) or kbuf (z=1); acc1 -> vt transposed (z=1 only)
  u16* out0 = z ? kbuf : qbuf;
  #pragma unroll
  for (int m = 0; m < 2; ++m) {
    int rowg = row0 + wr*32 + m*16 + lg*4;
    #pragma unroll
    for (int n = 0; n < 2; ++n) {
      int colg = col0 + wc*32 + n*16 + l15;
      float bvv = bias0[colg] * bscale;
      #pragma unroll
      for (int r = 0; r < 4; ++r)
        out0[(size_t)(rowg + r)*512 + colg] = f2bf(acc0[m][n][r] + bvv);
    }
  }
  if (z) {
    #pragma unroll
    for (int m = 0; m < 2; ++m) {
      int rowg = row0 + wr*32 + m*16 + lg*4;
      int b = rowg >> 11, ntok = rowg & 2047;
      #pragma unroll
      for (int n = 0; n < 2; ++n) {
        int colg = col0 + wc*32 + n*16 + l15;
        float bvv = bv[colg];
        u16x4 hv;
        #pragma unroll
        for (int r = 0; r < 4; ++r) hv[r] = f2bf(acc1[m][n][r] + bvv);
        *(u16x4*)(vt + ((size_t)b*512 + colg)*2048 + ntok) = hv;
      }
    }
  }
}

// ---------------- flash attention: 8 waves = 4 q-waves x 2 KV-halves, in-block combine --
__device__ __forceinline__ void mk_pb(const f32x16& s, float& ps, bf16x8& f0, bf16x8& f1) {
  float p[16];
  #pragma unroll
  for (int r = 0; r < 16; ++r) p[r] = __builtin_amdgcn_exp2f(s[r]);
  float t0 = (p[0] + p[1])  + (p[2] + p[3]);
  float t1 = (p[4] + p[5])  + (p[6] + p[7]);
  float t2 = (p[8] + p[9])  + (p[10] + p[11]);
  float t3 = (p[12] + p[13]) + (p[14] + p[15]);
  ps += (t0 + t1) + (t2 + t3);
  u32 a0 = cvtpk(p[0],  p[1]),  b0 = cvtpk(p[4],  p[5]);
  u32 a1 = cvtpk(p[2],  p[3]),  b1 = cvtpk(p[6],  p[7]);
  swap32(a0, b0); swap32(a1, b1);
  u32 a2 = cvtpk(p[8],  p[9]),  b2 = cvtpk(p[12], p[13]);
  u32 a3 = cvtpk(p[10], p[11]), b3 = cvtpk(p[14], p[15]);
  swap32(a2, b2); swap32(a3, b3);
  u32x4 w0 = {a0, a1, b0, b1};
  u32x4 w1 = {a2, a3, b2, b3};
  f0 = __builtin_bit_cast(bf16x8, w0);
  f1 = __builtin_bit_cast(bf16x8, w1);
}

__global__ __launch_bounds__(512, 4) void attn_k(
    const u16* __restrict__ qb, const u16* __restrict__ kb,
    const u16* __restrict__ vt, u16* __restrict__ ob)
{
  __shared__ __align__(16) char smem[65536];   // lK: 4x8KB | lV: 4x8KB; combine reuses lK

  int t = threadIdx.x, lane = t & 63, wid = t >> 6;
  int bh = blockIdx.y, b = bh >> 3, h = bh & 7;
  int half = wid >> 2;                         // KV half (0: 0-1023, 1: 1024-2047)
  int qw = wid & 3;
  int q0 = blockIdx.x * 128 + qw * 32;         // 4 q-waves x 32 rows
  int l31 = lane & 31, hi = lane >> 5;

  const u16* kbase = kb + ((size_t)b*2048)*512 + h*64;
  const u16* vbase = vt + ((size_t)b*512 + h*64)*2048;

  int sr = t >> 3;                                   // 0..63
  int ssrc = ((t & 7) ^ (sr & 7)) << 3;              // inverse-swizzled src col (elements)

#define LKB(hf, bf) (smem + ((hf)*2 + (bf))*8192)
#define LVB(hf, bf) (smem + 32768 + ((hf)*2 + (bf))*8192)
#define STAGE(buf, off)                                                           \
  gload16(kbase + (size_t)((off) + sr)*512 + ssrc,        LKB(0,buf) + t*16);     \
  gload16(kbase + (size_t)((off) + 1024 + sr)*512 + ssrc, LKB(1,buf) + t*16);     \
  gload16(vbase + (size_t)sr*2048 + (off) + ssrc,         LVB(0,buf) + t*16);     \
  gload16(vbase + (size_t)sr*2048 + (off) + 1024 + ssrc,  LVB(1,buf) + t*16);

  bf16x8 aq[4];
  {
    const u16* qp = qb + ((size_t)(b*2048 + q0 + l31))*512 + h*64 + hi*8;
    #pragma unroll
    for (int ks = 0; ks < 4; ++ks) aq[ks] = *(const bf16x8*)(qp + ks*16);
  }

  f32x16 acc[2] = {};
  float ps = 0.0f;

  STAGE(0, 0);
  __syncthreads();

  int cur = 0;
  for (int i = 0; i < 16; ++i) {
    if (i + 1 < 16) { STAGE(cur^1, (i+1)*64); }
    const char* lKc = LKB(half, cur);
    const char* lVc = LVB(half, cur);
    bf16x8 pb[4];
    #pragma unroll
    for (int n = 0; n < 2; ++n) {
      f32x16 s = {};
      #pragma unroll
      for (int ks = 0; ks < 4; ++ks) {
        bf16x8 kf = *(const bf16x8*)(lKc + swz(n*32 + l31, ks*32 + hi*16));
        s = MFMA32(kf, aq[ks], s);
      }
      mk_pb(s, ps, pb[2*n], pb[2*n+1]);
    }
    #pragma unroll
    for (int m = 0; m < 2; ++m)
      #pragma unroll
      for (int ks = 0; ks < 4; ++ks) {
        bf16x8 vf = *(const bf16x8*)(lVc + swz(m*32 + l31, ks*32 + hi*16));
        acc[m] = MFMA32(vf, pb[ks], acc[m]);
      }
    __syncthreads();
    cur ^= 1;
  }
#undef STAGE

  // ---- in-block combine: half-1 -> LDS (pitch 68 f32, region 2208 f32 per q-wave) ----
  ps += __shfl_xor(ps, 32, 64);
  float* cb = (float*)smem;
  if (half == 1) {
    float* dst = cb + qw * 2208;
    #pragma unroll
    for (int m = 0; m < 2; ++m)
      #pragma unroll
      for (int rq = 0; rq < 4; ++rq) {
        f32x4 v = {acc[m][rq*4], acc[m][rq*4+1], acc[m][rq*4+2], acc[m][rq*4+3]};
        *(f32x4*)(dst + l31*68 + m*32 + rq*8 + hi*4) = v;
      }
    if (hi == 0) dst[2176 + l31] = ps;
  }
  __syncthreads();
  if (half == 0) {
    const float* src = cb + qw * 2208;
    float inv = 1.0f / (ps + src[2176 + l31]);
    u16* obase = ob + ((size_t)(b*2048 + q0 + l31))*512 + h*64;
    const u16* qrb = qb + ((size_t)(b*2048 + q0 + l31))*512 + h*64;
    #pragma unroll
    for (int m = 0; m < 2; ++m)
      #pragma unroll
      for (int rq = 0; rq < 4; ++rq) {
        f32x4 other = *(const f32x4*)(src + l31*68 + m*32 + rq*8 + hi*4);
        u16x4 qr4 = *(const u16x4*)(qrb + m*32 + rq*8 + hi*4);
        u16x4 o4;
        #pragma unroll
        for (int e = 0; e < 4; ++e)
          o4[e] = f2bf((acc[m][rq*4 + e] + other[e])*inv + bf2f(qr4[e])*UNSCALE);
        *(u16x4*)(obase + m*32 + rq*8 + hi*4) = o4;
      }
  }
}

// ---------------- fused tail: LN0 (on-the-fly) -> Wo GEMM + ReLU + residual -> LN1 ------
// 32 rows x FULL 512 cols per block -> both LayerNorms are block-local.
// A staged reg->LDS with LN0 normalization applied; H residual recomputed from ob+stats;
// G never leaves registers: LN1 via per-wave partial sums + LDS cross-wave reduce.
__global__ __launch_bounds__(512) void tail_k(
    const u16* __restrict__ ob, const u16* __restrict__ Bt,
    const float* __restrict__ bo,
    const float* __restrict__ g0, const float* __restrict__ b0,
    const float* __restrict__ g1, const float* __restrict__ b1,
    float* __restrict__ out)
{
  __shared__ __align__(16) u16 lA[2][32*64];     // 4KB each
  __shared__ __align__(16) u16 lB[2][512*64];    // 64KB each
  __shared__ float mu0[32], rs0[32], mu1[32], rs1[32];
  __shared__ float ps1[32][8], ss1[32][8];

  int row0 = blockIdx.x * 32;
  int t = threadIdx.x, lane = t & 63, wid = t >> 6;
  int l15 = lane & 15, lg = lane >> 4;

  // ---- LN0 stats: 16 threads per row, 32 elems each ----
  {
    int r = t >> 4, c0 = (t & 15) * 32;
    const u16* xp = ob + (size_t)(row0 + r)*512 + c0;
    float s = 0.0f, ss = 0.0f;
    #pragma unroll
    for (int j = 0; j < 4; ++j) {
      u16x8 v = *(const u16x8*)(xp + j*8);
      #pragma unroll
      for (int e = 0; e < 8; ++e) { float f = bf2f(v[e]); s += f; ss += f*f; }
    }
    #pragma unroll
    for (int m = 1; m < 16; m <<= 1) { s += __shfl_xor(s, m, 64); ss += __shfl_xor(ss, m, 64); }
    if ((t & 15) == 0) {
      float mu = s * (1.0f/512.0f);
      float var = ss * (1.0f/512.0f) - mu*mu;
      mu0[r] = mu; rs0[r] = rsqrtf(var + 1e-5f);
    }
  }
  __syncthreads();

  int ar = t >> 3, ak8 = t & 7;                       // A staging (threads 0-255)
  int br = t >> 3;                                    // B staging rows 0..63 (+64i)
  int bsrc = ((t & 7) ^ (br & 7)) << 3;               // inverse-swizzled src col

  // stage A (normalized) into lA[buf] for K-slice k0
  auto stageA = [&](int buf, int k0) {
    if (t < 256) {
      u16x8 x = *(const u16x8*)(ob + (size_t)(row0 + ar)*512 + k0 + ak8*8);
      f32x4 gv0 = *(const f32x4*)(g0 + k0 + ak8*8);
      f32x4 gv1 = *(const f32x4*)(g0 + k0 + ak8*8 + 4);
      f32x4 bv0 = *(const f32x4*)(b0 + k0 + ak8*8);
      f32x4 bv1 = *(const f32x4*)(b0 + k0 + ak8*8 + 4);
      float mu = mu0[ar], rs = rs0[ar];
      u16x8 h;
      #pragma unroll
      for (int j = 0; j < 4; ++j) {
        h[j]   = f2bf((bf2f(x[j])   - mu)*rs*gv0[j] + bv0[j]);
        h[j+4] = f2bf((bf2f(x[j+4]) - mu)*rs*gv1[j] + bv1[j]);
      }
      *(u16x8*)((char*)lA[buf] + swz(ar, ak8*16)) = h;
    }
  };

  // prologue: stage k0=0
  #pragma unroll
  for (int i = 0; i < 8; ++i)
    gload16(Bt + (size_t)(br + i*64)*512 + bsrc, (char*)lB[0] + i*8192 + t*16);
  stageA(0, 0);
  __syncthreads();

  f32x4 acc[2][4] = {};
  int cur = 0;
  for (int k0 = 0; k0 < 512; k0 += 64) {
    if (k0 + 64 < 512) {
      #pragma unroll
      for (int i = 0; i < 8; ++i)
        gload16(Bt + (size_t)(br + i*64)*512 + k0 + 64 + bsrc, (char*)lB[cur^1] + i*8192 + t*16);
      stageA(cur^1, k0 + 64);
    }
    const char* lAc = (const char*)lA[cur];
    const char* lBc = (const char*)lB[cur];
    #pragma unroll
    for (int ks = 0; ks < 2; ++ks) {
      bf16x8 af[2], bfv[4];
      #pragma unroll
      for (int m = 0; m < 2; ++m)
        af[m] = *(const bf16x8*)(lAc + swz(m*16 + l15, ks*64 + lg*16));
      #pragma unroll
      for (int n = 0; n < 4; ++n)
        bfv[n] = *(const bf16x8*)(lBc + swz(wid*64 + n*16 + l15, ks*64 + lg*16));
      #pragma unroll
      for (int m = 0; m < 2; ++m)
        #pragma unroll
        for (int n = 0; n < 4; ++n)
          acc[m][n] = MFMA(af[m], bfv[n], acc[m][n]);
    }
    __syncthreads();
    cur ^= 1;
  }

  // ---- epilogue: G = H + relu(acc + bo); LN1 partials in-register ----
  float Gv[2][4][4];
  float sp[2][4] = {}, ssp[2][4] = {};
  #pragma unroll
  for (int n = 0; n < 4; ++n) {
    int colg = wid*64 + n*16 + l15;
    float bov = bo[colg];
    float g0c = g0[colg], b0c = b0[colg];
    #pragma unroll
    for (int m = 0; m < 2; ++m) {
      #pragma unroll
      for (int rr = 0; rr < 4; ++rr) {
        int rit = m*16 + lg*4 + rr;
        float H = (bf2f(ob[(size_t)(row0 + rit)*512 + colg]) - mu0[rit])*rs0[rit]*g0c + b0c;
        float G = H + fmaxf(acc[m][n][rr] + bov, 0.0f);
        Gv[m][n][rr] = G;
        sp[m][rr] += G;
        ssp[m][rr] += G*G;
      }
    }
  }
  #pragma unroll
  for (int msk = 1; msk < 16; msk <<= 1)
    #pragma unroll
    for (int m = 0; m < 2; ++m)
      #pragma unroll
      for (int rr = 0; rr < 4; ++rr) {
        sp[m][rr]  += __shfl_xor(sp[m][rr],  msk, 64);
        ssp[m][rr] += __shfl_xor(ssp[m][rr], msk, 64);
      }
  if (l15 == 0) {
    #pragma unroll
    for (int m = 0; m < 2; ++m)
      #pragma unroll
      for (int rr = 0; rr < 4; ++rr) {
        int rit = m*16 + lg*4 + rr;
        ps1[rit][wid] = sp[m][rr];
        ss1[rit][wid] = ssp[m][rr];
      }
  }
  __syncthreads();
  if (t < 32) {
    float s = 0.0f, ss = 0.0f;
    #pragma unroll
    for (int w = 0; w < 8; ++w) { s += ps1[t][w]; ss += ss1[t][w]; }
    float mu = s * (1.0f/512.0f);
    float var = ss * (1.0f/512.0f) - mu*mu;
    mu1[t] = mu; rs1[t] = rsqrtf(var + 1e-5f);
  }
  __syncthreads();
  #pragma unroll
  for (int n = 0; n < 4; ++n) {
    int colg = wid*64 + n*16 + l15;
    float g1c = g1[colg], b1c = b1[colg];
    #pragma unroll
    for (int m = 0; m < 2; ++m)
      #pragma unroll
      for (int rr = 0; rr < 4; ++rr) {
        int rit = m*16 + lg*4 + rr;
        out[(size_t)(row0 + rit)*512 + colg] =
            (Gv[m][n][rr] - mu1[rit])*rs1[rit]*g1c + b1c;
      }
  }
}

extern "C" void kernel_launch(void* const* d_in, const int* in_sizes, int n_in,
                              void* d_out, int out_size, void* d_ws, size_t ws_size,
                              hipStream_t stream)
{
  const float* Q   = (const float*)d_in[0];
  const float* K   = (const float*)d_in[1];
  const float* Wq  = (const float*)d_in[2];
  const float* bq  = (const float*)d_in[3];
  const float* Wk  = (const float*)d_in[4];
  const float* bk  = (const float*)d_in[5];
  const float* Wv  = (const float*)d_in[6];
  const float* bv  = (const float*)d_in[7];
  const float* Wo  = (const float*)d_in[8];
  const float* bo  = (const float*)d_in[9];
  const float* g0  = (const float*)d_in[10];
  const float* b0  = (const float*)d_in[11];
  const float* g1  = (const float*)d_in[12];
  const float* b1  = (const float*)d_in[13];

  char* ws = (char*)d_ws;
  // layout (MB): wt 0-2 | qbuf 2-10 | kbuf 10-18 | vt 18-26 | ob 26-34
  u16*   wt    = (u16*)(ws + 0);
  u16*   qbuf  = (u16*)(ws + (2u<<20));
  u16*   kbuf  = (u16*)(ws + (10u<<20));
  u16*   vt    = (u16*)(ws + (18u<<20));
  u16*   ob    = (u16*)(ws + (26u<<20));

  // 1. weight transpose+convert (Wq/bq scaled by 1/sqrt(512)*log2e)
  wprep_k<<<dim3(8, 8, 4), 256, 0, stream>>>(Wq, Wk, Wv, Wo, wt);
  // 2. projections: z=0 Q; z=1 K+V fused (K read once), V written pre-transposed
  proj2_k<<<dim3(128, 4, 2), 512, 0, stream>>>(Q, K, wt, bq, bk, bv, qbuf, kbuf, vt);
  // 3. attention, in-block KV-split + combine, residual added -> ob (bf16, final)
  attn_k<<<dim3(16, 32), 512, 0, stream>>>(qbuf, kbuf, vt, ob);
  // 4. fused tail: LN0 -> Wo GEMM + ReLU + residual -> LN1 -> out (fp32)
  tail_k<<<256, 512, 0, stream>>>(ob, wt + 3*262144, bo, g0, b0, g1, b1, (float*)d_out);
}